// Round 1
// baseline (2322.618 us; speedup 1.0000x reference)
//
#include <hip/hip_runtime.h>
#include <math.h>
#include <cstdint>

#define N_NODES 50000
#define F_IN    128
#define HIDDEN  256
#define NHEAD   4
#define HEADD   64
#define NEDGE   400000
#define NTYPE   2

__device__ __forceinline__ float lrelu(float x) { return x > 0.f ? x : 0.2f * x; }

// ============================ CSR build ============================
__global__ void hist_kernel(const int* __restrict__ dst0, const int* __restrict__ dst1,
                            int* __restrict__ counts) {
  int t = blockIdx.y;
  int e = blockIdx.x * blockDim.x + threadIdx.x;
  if (e >= NEDGE) return;
  const int* dst = t ? dst1 : dst0;
  atomicAdd(&counts[t * N_NODES + dst[e]], 1);
}

__launch_bounds__(1024)
__global__ void scan_kernel(const int* __restrict__ counts, int* __restrict__ row_ptr,
                            int* __restrict__ cursor) {
  int t = blockIdx.x;
  int tid = threadIdx.x;
  __shared__ int s[1024];
  int carry = 0;
  for (int base = 0; base < N_NODES; base += 1024) {
    int i = base + tid;
    int v = (i < N_NODES) ? counts[t * N_NODES + i] : 0;
    s[tid] = v;
    __syncthreads();
    for (int off = 1; off < 1024; off <<= 1) {
      int u = (tid >= off) ? s[tid - off] : 0;
      __syncthreads();
      s[tid] += u;
      __syncthreads();
    }
    if (i < N_NODES) {
      int excl = carry + s[tid] - v;
      row_ptr[t * (N_NODES + 1) + i] = excl;
      cursor[t * N_NODES + i] = excl;
    }
    carry += s[1023];
    __syncthreads();
  }
  if (tid == 0) row_ptr[t * (N_NODES + 1) + N_NODES] = carry;
}

__global__ void scatter_kernel(const int* __restrict__ src0, const int* __restrict__ dst0,
                               const int* __restrict__ src1, const int* __restrict__ dst1,
                               int* __restrict__ cursor, int* __restrict__ srcs) {
  int t = blockIdx.y;
  int e = blockIdx.x * blockDim.x + threadIdx.x;
  if (e >= NEDGE) return;
  const int* src = t ? src1 : src0;
  const int* dst = t ? dst1 : dst0;
  int d = dst[e];
  int pos = atomicAdd(&cursor[t * N_NODES + d], 1);
  srcs[t * NEDGE + pos] = src[e];
}

// ============================ GEMM ============================
// C[M,256] = epilogue( transform(A[M,K]) @ W[t][K,256] )
// MODE 0: GAT   — write z; accumulate el/er = sum_col z*al / z*ar (per head)
// MODE 1: GIN1  — write acc + bias
// MODE 2: GIN2  — A transformed by per-col BN scale/shift + relu; write relu(acc + bias)
// Tile: BM=64, BN=128, BK=32; 256 threads (16x16), each 4 rows x 8 cols
// (cols = {n0+tx*4..+3, n0+64+tx*4..+3} so each group lies in ONE head and
//  LDS reads are conflict-free)
template <int MODE>
__launch_bounds__(256)
__global__ void gemm_kernel(const float* __restrict__ A, long strideA, int ldA, int K,
                            const float* __restrict__ W,     // [T][K][256]
                            const float* __restrict__ bias,  // [T][256]   (MODE 1/2)
                            float* __restrict__ C, long strideC, int ldC, int colOffT,
                            const float* __restrict__ al,    // [T][256]   (MODE 0)
                            const float* __restrict__ ar,
                            float* __restrict__ el, float* __restrict__ er,  // [T][N][4]
                            const float* __restrict__ bnscale,               // [T][K] (MODE 2)
                            const float* __restrict__ bnshift,
                            int M) {
  constexpr int BM = 64, BN = 128, BK = 32;
  __shared__ float As[BK][BM + 4];
  __shared__ float Bs[BK][BN];
  const int t  = blockIdx.z;
  const int m0 = blockIdx.x * BM;
  const int n0 = blockIdx.y * BN;
  const int tid = threadIdx.x;
  const int ty = tid >> 4, tx = tid & 15;
  const float* At = A + (long)t * strideA;
  const float* Wt = W + (long)t * K * HIDDEN;
  const float* bsc = (MODE == 2) ? bnscale + (long)t * K : nullptr;
  const float* bsh = (MODE == 2) ? bnshift + (long)t * K : nullptr;

  float acc[4][8];
#pragma unroll
  for (int i = 0; i < 4; ++i)
#pragma unroll
    for (int j = 0; j < 8; ++j) acc[i][j] = 0.f;

  for (int k0 = 0; k0 < K; k0 += BK) {
    // ---- stage A (transposed) ----
    {
      int kq = (tid & 7) * 4;  // 0..28
      int r  = tid >> 3;       // 0..31
#pragma unroll
      for (int rr = 0; rr < 2; ++rr) {
        int row = m0 + r + rr * 32;
        float4 v = make_float4(0.f, 0.f, 0.f, 0.f);
        if (row < M) {
          v = *(const float4*)(At + (long)row * ldA + k0 + kq);
          if (MODE == 2) {
            v.x = fmaxf(fmaf(v.x, bsc[k0 + kq + 0], bsh[k0 + kq + 0]), 0.f);
            v.y = fmaxf(fmaf(v.y, bsc[k0 + kq + 1], bsh[k0 + kq + 1]), 0.f);
            v.z = fmaxf(fmaf(v.z, bsc[k0 + kq + 2], bsh[k0 + kq + 2]), 0.f);
            v.w = fmaxf(fmaf(v.w, bsc[k0 + kq + 3], bsh[k0 + kq + 3]), 0.f);
          }
        }
        As[kq + 0][r + rr * 32] = v.x;
        As[kq + 1][r + rr * 32] = v.y;
        As[kq + 2][r + rr * 32] = v.z;
        As[kq + 3][r + rr * 32] = v.w;
      }
    }
    // ---- stage B ----
    {
      int nq = (tid & 31) * 4;  // 0..124
      int kr = tid >> 5;        // 0..7
#pragma unroll
      for (int kk = 0; kk < 4; ++kk) {
        int k = kr + kk * 8;
        *(float4*)&Bs[k][nq] = *(const float4*)(Wt + (long)(k0 + k) * HIDDEN + n0 + nq);
      }
    }
    __syncthreads();
#pragma unroll
    for (int k = 0; k < BK; ++k) {
      float a[4], b[8];
      *(float4*)a = *(const float4*)&As[k][ty * 4];
      *(float4*)&b[0] = *(const float4*)&Bs[k][tx * 4];
      *(float4*)&b[4] = *(const float4*)&Bs[k][64 + tx * 4];
#pragma unroll
      for (int i = 0; i < 4; ++i)
#pragma unroll
        for (int j = 0; j < 8; ++j) acc[i][j] = fmaf(a[i], b[j], acc[i][j]);
    }
    __syncthreads();
  }

  const int colOff = colOffT * t;
  float* Ct = C + (long)t * strideC;

  if (MODE == 0) {
    const float* alt = al + t * HIDDEN;
    const float* art = ar + t * HIDDEN;
#pragma unroll
    for (int i = 0; i < 4; ++i) {
      int row = m0 + ty * 4 + i;
      if (row >= M) break;
      float pel0 = 0, per0 = 0, pel1 = 0, per1 = 0;
#pragma unroll
      for (int j = 0; j < 4; ++j) {
        int c0 = n0 + tx * 4 + j;
        int c1 = n0 + 64 + tx * 4 + j;
        float z0 = acc[i][j], z1 = acc[i][4 + j];
        pel0 = fmaf(z0, alt[c0], pel0);
        per0 = fmaf(z0, art[c0], per0);
        pel1 = fmaf(z1, alt[c1], pel1);
        per1 = fmaf(z1, art[c1], per1);
      }
      *(float4*)(Ct + (long)row * ldC + n0 + tx * 4)      = *(float4*)&acc[i][0];
      *(float4*)(Ct + (long)row * ldC + n0 + 64 + tx * 4) = *(float4*)&acc[i][4];
      // reduce over the 16 lanes sharing this row (tx=0..15, same ty → same wave)
#pragma unroll
      for (int off = 1; off < 16; off <<= 1) {
        pel0 += __shfl_xor(pel0, off);
        per0 += __shfl_xor(per0, off);
        pel1 += __shfl_xor(pel1, off);
        per1 += __shfl_xor(per1, off);
      }
      if (tx == 0) {
        int h0 = n0 / 64;
        atomicAdd(&el[(long)t * N_NODES * 4 + (long)row * 4 + h0],     pel0);
        atomicAdd(&er[(long)t * N_NODES * 4 + (long)row * 4 + h0],     per0);
        atomicAdd(&el[(long)t * N_NODES * 4 + (long)row * 4 + h0 + 1], pel1);
        atomicAdd(&er[(long)t * N_NODES * 4 + (long)row * 4 + h0 + 1], per1);
      }
    }
  } else {
    const float* bt = bias + t * HIDDEN;
    float b0[4], b1[4];
#pragma unroll
    for (int j = 0; j < 4; ++j) {
      b0[j] = bt[n0 + tx * 4 + j];
      b1[j] = bt[n0 + 64 + tx * 4 + j];
    }
#pragma unroll
    for (int i = 0; i < 4; ++i) {
      int row = m0 + ty * 4 + i;
      if (row >= M) break;
      float o0[4], o1[4];
#pragma unroll
      for (int j = 0; j < 4; ++j) {
        o0[j] = acc[i][j] + b0[j];
        o1[j] = acc[i][4 + j] + b1[j];
        if (MODE == 2) { o0[j] = fmaxf(o0[j], 0.f); o1[j] = fmaxf(o1[j], 0.f); }
      }
      float* cp = Ct + (long)row * ldC + colOff;
      *(float4*)(cp + n0 + tx * 4)      = *(float4*)o0;
      *(float4*)(cp + n0 + 64 + tx * 4) = *(float4*)o1;
    }
  }
}

// ============================ GAT aggregation ============================
// one wave per dst node; CSR edges sorted by dst → zero atomics
__launch_bounds__(256)
__global__ void gat_agg_kernel(const float* __restrict__ z,   // [T][N][256]
                               const float* __restrict__ el,  // [T][N][4]
                               const float* __restrict__ er,  // [T][N][4]
                               const int* __restrict__ row_ptr,
                               const int* __restrict__ srcs,
                               const float* __restrict__ bias,  // [T][256]
                               float* __restrict__ hout) {      // [T][N][256]
  int t = blockIdx.y;
  int wv = threadIdx.x >> 6, lane = threadIdx.x & 63;
  int dst = blockIdx.x * 4 + wv;
  if (dst >= N_NODES) return;
  const int* rp = row_ptr + t * (N_NODES + 1);
  int beg = rp[dst], end = rp[dst + 1];
  const float* elt = el + (long)t * N_NODES * 4;
  const float* zt  = z + (long)t * N_NODES * HIDDEN;
  const int* st = srcs + (long)t * NEDGE;
  float4 erd = *(const float4*)(er + (long)t * N_NODES * 4 + (long)dst * 4);

  // pass 1: per-head max
  float m0 = -INFINITY, m1 = -INFINITY, m2 = -INFINITY, m3 = -INFINITY;
  for (int j = beg + lane; j < end; j += 64) {
    int s = st[j];
    float4 ev = *(const float4*)(elt + (long)s * 4);
    m0 = fmaxf(m0, lrelu(ev.x + erd.x));
    m1 = fmaxf(m1, lrelu(ev.y + erd.y));
    m2 = fmaxf(m2, lrelu(ev.z + erd.z));
    m3 = fmaxf(m3, lrelu(ev.w + erd.w));
  }
#pragma unroll
  for (int off = 32; off; off >>= 1) {
    m0 = fmaxf(m0, __shfl_xor(m0, off));
    m1 = fmaxf(m1, __shfl_xor(m1, off));
    m2 = fmaxf(m2, __shfl_xor(m2, off));
    m3 = fmaxf(m3, __shfl_xor(m3, off));
  }
  // pass 2: denominator
  float d0 = 0, d1 = 0, d2 = 0, d3 = 0;
  for (int j = beg + lane; j < end; j += 64) {
    int s = st[j];
    float4 ev = *(const float4*)(elt + (long)s * 4);
    d0 += __expf(lrelu(ev.x + erd.x) - m0);
    d1 += __expf(lrelu(ev.y + erd.y) - m1);
    d2 += __expf(lrelu(ev.z + erd.z) - m2);
    d3 += __expf(lrelu(ev.w + erd.w) - m3);
  }
#pragma unroll
  for (int off = 32; off; off >>= 1) {
    d0 += __shfl_xor(d0, off);
    d1 += __shfl_xor(d1, off);
    d2 += __shfl_xor(d2, off);
    d3 += __shfl_xor(d3, off);
  }
  // pass 3: weighted aggregation; lane owns cols 4*lane..+3; head = lane>>4
  int hl = lane >> 4;
  float mh  = (hl == 0) ? m0 : (hl == 1) ? m1 : (hl == 2) ? m2 : m3;
  float dh  = (hl == 0) ? d0 : (hl == 1) ? d1 : (hl == 2) ? d2 : d3;
  float erh = (hl == 0) ? erd.x : (hl == 1) ? erd.y : (hl == 2) ? erd.z : erd.w;
  float inv = 1.0f / fmaxf(dh, 1e-9f);
  float a0 = 0, a1 = 0, a2 = 0, a3 = 0;
  for (int j = beg; j < end; ++j) {
    int s = st[j];
    float eh = lrelu(elt[(long)s * 4 + hl] + erh);
    float w = __expf(eh - mh) * inv;
    float4 zv = *(const float4*)(zt + (long)s * HIDDEN + lane * 4);
    a0 = fmaf(w, zv.x, a0);
    a1 = fmaf(w, zv.y, a1);
    a2 = fmaf(w, zv.z, a2);
    a3 = fmaf(w, zv.w, a3);
  }
  float4 bv = *(const float4*)(bias + t * HIDDEN + lane * 4);
  float4 o;
  o.x = fmaxf(a0 + bv.x, 0.f);
  o.y = fmaxf(a1 + bv.y, 0.f);
  o.z = fmaxf(a2 + bv.z, 0.f);
  o.w = fmaxf(a3 + bv.w, 0.f);
  *(float4*)(hout + (long)t * N_NODES * HIDDEN + (long)dst * HIDDEN + lane * 4) = o;
}

// ============================ GIN pre (sum-agg + (1+eps)*self) ============================
template <bool HASF>
__launch_bounds__(256)
__global__ void gin_pre_kernel(const float* __restrict__ h,      // [T][N][256]
                               const float* __restrict__ feats,  // [N][128] (HASF)
                               const int* __restrict__ row_ptr,
                               const int* __restrict__ srcs,
                               const float* __restrict__ epsArr,  // [T]
                               float* __restrict__ x, long strideX, int ldX) {
  int t = blockIdx.y;
  int wv = threadIdx.x >> 6, lane = threadIdx.x & 63;
  int dst = blockIdx.x * 4 + wv;
  if (dst >= N_NODES) return;
  const int* rp = row_ptr + t * (N_NODES + 1);
  int beg = rp[dst], end = rp[dst + 1];
  const float* ht = h + (long)t * N_NODES * HIDDEN;
  const int* st = srcs + (long)t * NEDGE;
  float ep = 1.0f + epsArr[t];
  float a0 = 0, a1 = 0, a2 = 0, a3 = 0, f0 = 0, f1 = 0;
  for (int j = beg; j < end; ++j) {
    int s = st[j];
    float4 hv = *(const float4*)(ht + (long)s * HIDDEN + lane * 4);
    a0 += hv.x; a1 += hv.y; a2 += hv.z; a3 += hv.w;
    if (HASF) {
      float2 fv = *(const float2*)(feats + (long)s * F_IN + lane * 2);
      f0 += fv.x; f1 += fv.y;
    }
  }
  float4 hs = *(const float4*)(ht + (long)dst * HIDDEN + lane * 4);
  float* xt = x + (long)t * strideX + (long)dst * ldX;
  float4 o;
  o.x = fmaf(ep, hs.x, a0);
  o.y = fmaf(ep, hs.y, a1);
  o.z = fmaf(ep, hs.z, a2);
  o.w = fmaf(ep, hs.w, a3);
  *(float4*)(xt + lane * 4) = o;
  if (HASF) {
    float2 fs = *(const float2*)(feats + (long)dst * F_IN + lane * 2);
    float2 of;
    of.x = fmaf(ep, fs.x, f0);
    of.y = fmaf(ep, fs.y, f1);
    *(float2*)(xt + HIDDEN + lane * 2) = of;
  }
}

// ============================ BN stats ============================
__launch_bounds__(256)
__global__ void stats_kernel(const float* __restrict__ y, long strideY,
                             float* __restrict__ sums) {  // [T][2][256]
  int t = blockIdx.y;
  int col = threadIdx.x;  // 256
  int r0 = blockIdx.x * 512;
  const float* yt = y + (long)t * strideY;
  float s = 0, s2 = 0;
  int rend = min(r0 + 512, N_NODES);
  for (int r = r0; r < rend; ++r) {
    float v = yt[(long)r * HIDDEN + col];
    s += v;
    s2 = fmaf(v, v, s2);
  }
  atomicAdd(&sums[t * 2 * HIDDEN + col], s);
  atomicAdd(&sums[t * 2 * HIDDEN + HIDDEN + col], s2);
}

__global__ void bn_finalize_kernel(const float* __restrict__ sums,
                                   const float* __restrict__ g1,   // [T][256]
                                   const float* __restrict__ be1,  // [T][256]
                                   float* __restrict__ scale, float* __restrict__ shift) {
  int i = threadIdx.x + blockIdx.x * blockDim.x;
  if (i >= NTYPE * HIDDEN) return;
  int t = i / HIDDEN, c = i % HIDDEN;
  float mu  = sums[t * 2 * HIDDEN + c] * (1.0f / N_NODES);
  float ms  = sums[t * 2 * HIDDEN + HIDDEN + c] * (1.0f / N_NODES);
  float var = ms - mu * mu;
  float sc = g1[i] * rsqrtf(var + 1e-5f);
  scale[i] = sc;
  shift[i] = be1[i] - mu * sc;
}

// ============================ launch ============================
extern "C" void kernel_launch(void* const* d_in, const int* in_sizes, int n_in,
                              void* d_out, int out_size, void* d_ws, size_t ws_size,
                              hipStream_t stream) {
  const float* feats   = (const float*)d_in[0];
  const int* src0      = (const int*)d_in[1];
  const int* dst0      = (const int*)d_in[2];
  const int* src1      = (const int*)d_in[3];
  const int* dst1      = (const int*)d_in[4];
  const float* gat0_W  = (const float*)d_in[5];
  const float* gat0_al = (const float*)d_in[6];
  const float* gat0_ar = (const float*)d_in[7];
  const float* gat0_b  = (const float*)d_in[8];
  const float* gat1_W  = (const float*)d_in[9];
  const float* gat1_al = (const float*)d_in[10];
  const float* gat1_ar = (const float*)d_in[11];
  const float* gat1_b  = (const float*)d_in[12];
  const float* gin0_eps = (const float*)d_in[13];
  const float* gin0_W1  = (const float*)d_in[14];
  const float* gin0_b1  = (const float*)d_in[15];
  const float* gin0_g1  = (const float*)d_in[16];
  const float* gin0_be1 = (const float*)d_in[17];
  const float* gin0_W2  = (const float*)d_in[18];
  const float* gin0_b2  = (const float*)d_in[19];
  const float* gin1_eps = (const float*)d_in[20];
  const float* gin1_W1  = (const float*)d_in[21];
  const float* gin1_b1  = (const float*)d_in[22];
  const float* gin1_g1  = (const float*)d_in[23];
  const float* gin1_be1 = (const float*)d_in[24];
  const float* gin1_W2  = (const float*)d_in[25];
  const float* gin1_b2  = (const float*)d_in[26];
  float* out = (float*)d_out;

  char* p = (char*)d_ws;
  size_t off = 0;
  auto take = [&](size_t bytes) -> void* {
    void* r = p + off;
    off = (off + bytes + 255) & ~(size_t)255;
    return r;
  };
  float* bufA = (float*)take((size_t)NTYPE * N_NODES * 384 * 4);     // x (GIN in, up to 384 wide)
  float* bufB = (float*)take((size_t)NTYPE * N_NODES * HIDDEN * 4);  // z / y
  float* bufC = (float*)take((size_t)NTYPE * N_NODES * HIDDEN * 4);  // h
  float* el   = (float*)take((size_t)NTYPE * N_NODES * 4 * 4);
  float* er   = (float*)take((size_t)NTYPE * N_NODES * 4 * 4);
  int* counts  = (int*)take((size_t)NTYPE * N_NODES * 4);
  int* row_ptr = (int*)take((size_t)NTYPE * (N_NODES + 1) * 4);
  int* cursor  = (int*)take((size_t)NTYPE * N_NODES * 4);
  int* srcs    = (int*)take((size_t)NTYPE * NEDGE * 4);
  float* bn_sums  = (float*)take((size_t)NTYPE * 2 * HIDDEN * 4);
  float* bn_scale = (float*)take((size_t)NTYPE * HIDDEN * 4);
  float* bn_shift = (float*)take((size_t)NTYPE * HIDDEN * 4);
  (void)ws_size; (void)in_sizes; (void)n_in; (void)out_size;

  const dim3 blk(256);
  const int egrid = (NEDGE + 255) / 256;
  const dim3 ggrid((N_NODES + 63) / 64, 2, NTYPE);
  const dim3 agrid((N_NODES + 3) / 4, NTYPE);
  const size_t elersz = 2 * (size_t)NTYPE * N_NODES * 4 * sizeof(float);
  const long sN256 = (long)N_NODES * HIDDEN;

  // ---- CSR build (recomputed every call: inputs restored pre-launch) ----
  hipMemsetAsync(counts, 0, (size_t)NTYPE * N_NODES * 4, stream);
  hist_kernel<<<dim3(egrid, NTYPE), blk, 0, stream>>>(dst0, dst1, counts);
  scan_kernel<<<NTYPE, 1024, 0, stream>>>(counts, row_ptr, cursor);
  scatter_kernel<<<dim3(egrid, NTYPE), blk, 0, stream>>>(src0, dst0, src1, dst1, cursor, srcs);

  // ---- GAT layer 0 (K = 128, A = feats shared across types) ----
  hipMemsetAsync(el, 0, elersz, stream);
  gemm_kernel<0><<<ggrid, blk, 0, stream>>>(feats, 0L, F_IN, F_IN, gat0_W, nullptr,
      bufB, sN256, HIDDEN, 0, gat0_al, gat0_ar, el, er, nullptr, nullptr, N_NODES);
  gat_agg_kernel<<<agrid, blk, 0, stream>>>(bufB, el, er, row_ptr, srcs, gat0_b, bufC);

  // ---- GAT layer 1 (K = 256) ----
  hipMemsetAsync(el, 0, elersz, stream);
  gemm_kernel<0><<<ggrid, blk, 0, stream>>>(bufC, sN256, HIDDEN, HIDDEN, gat1_W, nullptr,
      bufB, sN256, HIDDEN, 0, gat1_al, gat1_ar, el, er, nullptr, nullptr, N_NODES);
  gat_agg_kernel<<<agrid, blk, 0, stream>>>(bufB, el, er, row_ptr, srcs, gat1_b, bufC);

  // ---- GIN layer 0 (skip-concat: x = [(1+e)h+agg(h) | (1+e)f+agg(f)], K = 384) ----
  gin_pre_kernel<true><<<agrid, blk, 0, stream>>>(bufC, feats, row_ptr, srcs, gin0_eps,
      bufA, (long)N_NODES * 384, 384);
  hipMemsetAsync(bn_sums, 0, (size_t)NTYPE * 2 * HIDDEN * 4, stream);
  gemm_kernel<1><<<ggrid, blk, 0, stream>>>(bufA, (long)N_NODES * 384, 384, 384, gin0_W1, gin0_b1,
      bufB, sN256, HIDDEN, 0, nullptr, nullptr, nullptr, nullptr, nullptr, nullptr, N_NODES);
  stats_kernel<<<dim3((N_NODES + 511) / 512, NTYPE), blk, 0, stream>>>(bufB, sN256, bn_sums);
  bn_finalize_kernel<<<1, NTYPE * HIDDEN, 0, stream>>>(bn_sums, gin0_g1, gin0_be1, bn_scale, bn_shift);
  gemm_kernel<2><<<ggrid, blk, 0, stream>>>(bufB, sN256, HIDDEN, HIDDEN, gin0_W2, gin0_b2,
      bufC, sN256, HIDDEN, 0, nullptr, nullptr, nullptr, nullptr, bn_scale, bn_shift, N_NODES);

  // ---- GIN layer 1 (K = 256) ----
  gin_pre_kernel<false><<<agrid, blk, 0, stream>>>(bufC, nullptr, row_ptr, srcs, gin1_eps,
      bufA, sN256, HIDDEN);
  hipMemsetAsync(bn_sums, 0, (size_t)NTYPE * 2 * HIDDEN * 4, stream);
  gemm_kernel<1><<<ggrid, blk, 0, stream>>>(bufA, sN256, HIDDEN, HIDDEN, gin1_W1, gin1_b1,
      bufB, sN256, HIDDEN, 0, nullptr, nullptr, nullptr, nullptr, nullptr, nullptr, N_NODES);
  stats_kernel<<<dim3((N_NODES + 511) / 512, NTYPE), blk, 0, stream>>>(bufB, sN256, bn_sums);
  bn_finalize_kernel<<<1, NTYPE * HIDDEN, 0, stream>>>(bn_sums, gin1_g1, gin1_be1, bn_scale, bn_shift);
  // final: write straight into d_out[N, 512] at column offset t*256
  gemm_kernel<2><<<ggrid, blk, 0, stream>>>(bufB, sN256, HIDDEN, HIDDEN, gin1_W2, gin1_b2,
      out, 0L, NTYPE * HIDDEN, HIDDEN, nullptr, nullptr, nullptr, nullptr, bn_scale, bn_shift, N_NODES);
}

// Round 3
// 1951.152 us; speedup vs baseline: 1.1904x; 1.1904x over previous
//
#include <hip/hip_runtime.h>
#include <math.h>
#include <cstdint>

#define N_NODES 50000
#define F_IN    128
#define HIDDEN  256
#define NHEAD   4
#define HEADD   64
#define NEDGE   400000
#define NTYPE   2

typedef unsigned short u16;
typedef float f32x4 __attribute__((ext_vector_type(4)));
typedef short s16x8 __attribute__((ext_vector_type(8)));

__device__ __forceinline__ float lrelu(float x) { return x > 0.f ? x : 0.2f * x; }

// ============================ CSR build ============================
__global__ void hist_kernel(const int* __restrict__ dst0, const int* __restrict__ dst1,
                            int* __restrict__ counts) {
  int t = blockIdx.y;
  int e = blockIdx.x * blockDim.x + threadIdx.x;
  if (e >= NEDGE) return;
  const int* dst = t ? dst1 : dst0;
  atomicAdd(&counts[t * N_NODES + dst[e]], 1);
}

__launch_bounds__(1024)
__global__ void scan_kernel(const int* __restrict__ counts, int* __restrict__ row_ptr,
                            int* __restrict__ cursor) {
  int t = blockIdx.x;
  int tid = threadIdx.x;
  __shared__ int s[1024];
  int carry = 0;
  for (int base = 0; base < N_NODES; base += 1024) {
    int i = base + tid;
    int v = (i < N_NODES) ? counts[t * N_NODES + i] : 0;
    s[tid] = v;
    __syncthreads();
    for (int off = 1; off < 1024; off <<= 1) {
      int u = (tid >= off) ? s[tid - off] : 0;
      __syncthreads();
      s[tid] += u;
      __syncthreads();
    }
    if (i < N_NODES) {
      int excl = carry + s[tid] - v;
      row_ptr[t * (N_NODES + 1) + i] = excl;
      cursor[t * N_NODES + i] = excl;
    }
    carry += s[1023];
    __syncthreads();
  }
  if (tid == 0) row_ptr[t * (N_NODES + 1) + N_NODES] = carry;
}

__global__ void scatter_kernel(const int* __restrict__ src0, const int* __restrict__ dst0,
                               const int* __restrict__ src1, const int* __restrict__ dst1,
                               int* __restrict__ cursor, int* __restrict__ srcs) {
  int t = blockIdx.y;
  int e = blockIdx.x * blockDim.x + threadIdx.x;
  if (e >= NEDGE) return;
  const int* src = t ? src1 : src0;
  const int* dst = t ? dst1 : dst0;
  int d = dst[e];
  int pos = atomicAdd(&cursor[t * N_NODES + d], 1);
  srcs[t * NEDGE + pos] = src[e];
}

// ============================ weight prep: transpose + bf16 hi/lo split ============================
// W[t][K][256] fp32  ->  Bth/Btl[t][256][K] bf16 (u16 bit patterns)
__launch_bounds__(256)
__global__ void prep_b_kernel(const float* __restrict__ W, u16* __restrict__ bth,
                              u16* __restrict__ btl, int K) {
  __shared__ unsigned tile[64][65];
  const int kt = blockIdx.x * 64, nt = blockIdx.y * 64, t = blockIdx.z;
  const int tid = threadIdx.x;
  const float* Wt = W + (size_t)t * K * 256;
  {
    int k = tid >> 2;             // 0..63
    int ncl = (tid & 3) * 16;     // 0,16,32,48
#pragma unroll
    for (int q = 0; q < 4; ++q) {
      float4 v = *(const float4*)(Wt + (size_t)(kt + k) * 256 + nt + ncl + q * 4);
      float f[4] = {v.x, v.y, v.z, v.w};
#pragma unroll
      for (int e = 0; e < 4; ++e) {
        unsigned u = __float_as_uint(f[e]);
        unsigned hi = u >> 16;
        float hf = __uint_as_float(u & 0xffff0000u);
        float l = f[e] - hf;
        unsigned lo = __float_as_uint(l) >> 16;
        tile[k][ncl + q * 4 + e] = hi | (lo << 16);
      }
    }
  }
  __syncthreads();
  {
    int n = tid & 63;
    int kc = (tid >> 6) * 16;  // 0,16,32,48
    u16 hi16[16], lo16[16];
#pragma unroll
    for (int i = 0; i < 16; ++i) {
      unsigned u = tile[kc + i][n];
      hi16[i] = (u16)(u & 0xffff);
      lo16[i] = (u16)(u >> 16);
    }
    size_t ob = ((size_t)t * 256 + nt + n) * K + kt + kc;
    *(s16x8*)(bth + ob)     = *(s16x8*)&hi16[0];
    *(s16x8*)(bth + ob + 8) = *(s16x8*)&hi16[8];
    *(s16x8*)(btl + ob)     = *(s16x8*)&lo16[0];
    *(s16x8*)(btl + ob + 8) = *(s16x8*)&lo16[8];
  }
}

// ============================ MFMA GEMM (bf16 3-term split, fp32 out) ============================
// C[M,256] = epilogue( transform(A[M,K]) @ W[t][K,256] )
// MODE 0: GAT  — write z; el/er = sum_col z*al / z*ar (per head, fused)
// MODE 1: GIN1 — write acc + bias
// MODE 2: GIN2 — A transformed by per-col BN scale/shift + relu; write relu(acc+bias)
// Tile BM=128,BN=128,BK=64; 256 threads = 4 waves (2m x 2n), 64x64 per wave.
// LDS bf16 tiles [row][64] with 16B-chunk XOR swizzle: slot = c ^ (row&7)
// (same involution on write and read — conflict-free ds_read_b128).
template <int MODE>
__launch_bounds__(256)
__global__ void gemm_mfma(const float* __restrict__ A, long strideA, int ldA, int K,
                          const u16* __restrict__ Bth, const u16* __restrict__ Btl,
                          const float* __restrict__ bias,
                          float* __restrict__ C, long strideC, int ldC, int colOffT,
                          const float* __restrict__ al, const float* __restrict__ ar,
                          float* __restrict__ el, float* __restrict__ er,
                          const float* __restrict__ bnscale, const float* __restrict__ bnshift,
                          int M) {
  __shared__ __align__(16) char lds[65536];
  char* Ah = lds;
  char* Al = lds + 16384;
  char* Bh = lds + 32768;
  char* Bl = lds + 49152;

  const int t  = blockIdx.z;
  const int m0 = blockIdx.x * 128;
  const int n0 = blockIdx.y * 128;
  const int tid = threadIdx.x;
  const int lane = tid & 63;
  const int wid = tid >> 6;
  const int wm = wid >> 1, wn = wid & 1;
  const int lm = lane & 15, lg = lane >> 4;

  const float* At = A + (long)t * strideA;
  const float* bsc = (MODE == 2) ? bnscale + (long)t * K : nullptr;
  const float* bsh = (MODE == 2) ? bnshift + (long)t * K : nullptr;

  f32x4 acc[4][4];
#pragma unroll
  for (int i = 0; i < 4; ++i)
#pragma unroll
    for (int j = 0; j < 4; ++j) acc[i][j] = (f32x4)(0.f);

  // staging assignments
  const int ar_ = tid >> 1;        // A row 0..127
  const int akh = tid & 1;         // A k-half (32 floats)
  const bool avalid = (m0 + ar_) < M;
  const int bn_ = tid >> 1;        // B row (n) 0..127
  const int bs_ = tid & 1;         // 0 = hi, 1 = lo
  const u16* bsrc = (bs_ ? Btl : Bth) + ((size_t)t * 256 + n0 + bn_) * K;
  char* bdst = bs_ ? Bl : Bh;

  for (int k0 = 0; k0 < K; k0 += 64) {
    if (k0) __syncthreads();
    // ---- stage A: fp32 -> hi/lo bf16, swizzled ----
    {
      float fv[32];
      const float* ap = At + (long)(m0 + ar_) * ldA + k0 + akh * 32;
#pragma unroll
      for (int q = 0; q < 8; ++q) {
        float4 v = make_float4(0.f, 0.f, 0.f, 0.f);
        if (avalid) {
          v = *(const float4*)(ap + q * 4);
          if (MODE == 2) {
            int kb = k0 + akh * 32 + q * 4;
            float4 sc = *(const float4*)(bsc + kb);
            float4 sh = *(const float4*)(bsh + kb);
            v.x = fmaxf(fmaf(v.x, sc.x, sh.x), 0.f);
            v.y = fmaxf(fmaf(v.y, sc.y, sh.y), 0.f);
            v.z = fmaxf(fmaf(v.z, sc.z, sh.z), 0.f);
            v.w = fmaxf(fmaf(v.w, sc.w, sh.w), 0.f);
          }
        }
        fv[q * 4 + 0] = v.x; fv[q * 4 + 1] = v.y; fv[q * 4 + 2] = v.z; fv[q * 4 + 3] = v.w;
      }
#pragma unroll
      for (int cl = 0; cl < 4; ++cl) {
        u16 hi[8], lo[8];
#pragma unroll
        for (int e = 0; e < 8; ++e) {
          float f = fv[cl * 8 + e];
          unsigned u = __float_as_uint(f);
          hi[e] = (u16)(u >> 16);
          float hf = __uint_as_float(u & 0xffff0000u);
          float l = f - hf;
          lo[e] = (u16)(__float_as_uint(l) >> 16);
        }
        int c = akh * 4 + cl;
        int off = ar_ * 128 + ((c ^ (ar_ & 7)) << 4);
        *(s16x8*)(Ah + off) = *(s16x8*)&hi[0];
        *(s16x8*)(Al + off) = *(s16x8*)&lo[0];
      }
    }
    // ---- stage B: pre-split bf16, swizzled ----
    {
      const u16* bp = bsrc + k0;
#pragma unroll
      for (int c = 0; c < 8; ++c) {
        s16x8 v = *(const s16x8*)(bp + c * 8);
        *(s16x8*)(bdst + bn_ * 128 + ((c ^ (bn_ & 7)) << 4)) = v;
      }
    }
    __syncthreads();
    // ---- MFMA ----
#pragma unroll
    for (int kk = 0; kk < 2; ++kk) {
      int c = kk * 4 + lg;
      s16x8 fAh[4], fAl[4], fBh[4], fBl[4];
#pragma unroll
      for (int i = 0; i < 4; ++i) {
        int m = wm * 64 + i * 16 + lm;
        int off = m * 128 + ((c ^ (m & 7)) << 4);
        fAh[i] = *(const s16x8*)(Ah + off);
        fAl[i] = *(const s16x8*)(Al + off);
      }
#pragma unroll
      for (int j = 0; j < 4; ++j) {
        int n = wn * 64 + j * 16 + lm;
        int off = n * 128 + ((c ^ (n & 7)) << 4);
        fBh[j] = *(const s16x8*)(Bh + off);
        fBl[j] = *(const s16x8*)(Bl + off);
      }
#pragma unroll
      for (int i = 0; i < 4; ++i)
#pragma unroll
        for (int j = 0; j < 4; ++j) {
          acc[i][j] = __builtin_amdgcn_mfma_f32_16x16x32_bf16(fAh[i], fBh[j], acc[i][j], 0, 0, 0);
          acc[i][j] = __builtin_amdgcn_mfma_f32_16x16x32_bf16(fAh[i], fBl[j], acc[i][j], 0, 0, 0);
          acc[i][j] = __builtin_amdgcn_mfma_f32_16x16x32_bf16(fAl[i], fBh[j], acc[i][j], 0, 0, 0);
        }
    }
  }

  // ---- epilogue ----
  const int colOff = colOffT * t;
  float* Ct = C + (long)t * strideC + colOff;

  if (MODE == 0) {
    const float* alt = al + t * HIDDEN;
    const float* art = ar + t * HIDDEN;
    const int head = (n0 + wn * 64) >> 6;  // one head per wave (64-col wave tile)
    float av[4], rv[4];
#pragma unroll
    for (int j = 0; j < 4; ++j) {
      int gc = n0 + wn * 64 + j * 16 + lm;
      av[j] = alt[gc];
      rv[j] = art[gc];
    }
#pragma unroll
    for (int i = 0; i < 4; ++i)
#pragma unroll
      for (int r = 0; r < 4; ++r) {
        float pel = 0.f, per = 0.f;
#pragma unroll
        for (int j = 0; j < 4; ++j) {
          pel = fmaf(acc[i][j][r], av[j], pel);
          per = fmaf(acc[i][j][r], rv[j], per);
        }
#pragma unroll
        for (int o = 1; o < 16; o <<= 1) {
          pel += __shfl_xor(pel, o);
          per += __shfl_xor(per, o);
        }
        int row = m0 + wm * 64 + i * 16 + lg * 4 + r;
        if (lm == 0 && row < M) {
          atomicAdd(&el[((long)t * N_NODES + row) * 4 + head], pel);
          atomicAdd(&er[((long)t * N_NODES + row) * 4 + head], per);
        }
      }
  }

  float bv[4];
  if (MODE != 0) {
#pragma unroll
    for (int j = 0; j < 4; ++j) bv[j] = bias[t * HIDDEN + n0 + wn * 64 + j * 16 + lm];
  }
#pragma unroll
  for (int i = 0; i < 4; ++i)
#pragma unroll
    for (int r = 0; r < 4; ++r) {
      int row = m0 + wm * 64 + i * 16 + lg * 4 + r;
      if (row < M) {
#pragma unroll
        for (int j = 0; j < 4; ++j) {
          int col = n0 + wn * 64 + j * 16 + lm;
          float v = acc[i][j][r];
          if (MODE != 0) v += bv[j];
          if (MODE == 2) v = fmaxf(v, 0.f);
          Ct[(long)row * ldC + col] = v;
        }
      }
    }
}

// ============================ GAT aggregation ============================
__launch_bounds__(256)
__global__ void gat_agg_kernel(const float* __restrict__ z, const float* __restrict__ el,
                               const float* __restrict__ er, const int* __restrict__ row_ptr,
                               const int* __restrict__ srcs, const float* __restrict__ bias,
                               float* __restrict__ hout) {
  int t = blockIdx.y;
  int wv = threadIdx.x >> 6, lane = threadIdx.x & 63;
  int dst = blockIdx.x * 4 + wv;
  if (dst >= N_NODES) return;
  const int* rp = row_ptr + t * (N_NODES + 1);
  int beg = rp[dst], end = rp[dst + 1];
  const float* elt = el + (long)t * N_NODES * 4;
  const float* zt  = z + (long)t * N_NODES * HIDDEN;
  const int* st = srcs + (long)t * NEDGE;
  float4 erd = *(const float4*)(er + (long)t * N_NODES * 4 + (long)dst * 4);

  float m0 = -INFINITY, m1 = -INFINITY, m2 = -INFINITY, m3 = -INFINITY;
  for (int j = beg + lane; j < end; j += 64) {
    int s = st[j];
    float4 ev = *(const float4*)(elt + (long)s * 4);
    m0 = fmaxf(m0, lrelu(ev.x + erd.x));
    m1 = fmaxf(m1, lrelu(ev.y + erd.y));
    m2 = fmaxf(m2, lrelu(ev.z + erd.z));
    m3 = fmaxf(m3, lrelu(ev.w + erd.w));
  }
#pragma unroll
  for (int off = 32; off; off >>= 1) {
    m0 = fmaxf(m0, __shfl_xor(m0, off));
    m1 = fmaxf(m1, __shfl_xor(m1, off));
    m2 = fmaxf(m2, __shfl_xor(m2, off));
    m3 = fmaxf(m3, __shfl_xor(m3, off));
  }
  float d0 = 0, d1 = 0, d2 = 0, d3 = 0;
  for (int j = beg + lane; j < end; j += 64) {
    int s = st[j];
    float4 ev = *(const float4*)(elt + (long)s * 4);
    d0 += __expf(lrelu(ev.x + erd.x) - m0);
    d1 += __expf(lrelu(ev.y + erd.y) - m1);
    d2 += __expf(lrelu(ev.z + erd.z) - m2);
    d3 += __expf(lrelu(ev.w + erd.w) - m3);
  }
#pragma unroll
  for (int off = 32; off; off >>= 1) {
    d0 += __shfl_xor(d0, off);
    d1 += __shfl_xor(d1, off);
    d2 += __shfl_xor(d2, off);
    d3 += __shfl_xor(d3, off);
  }
  int hl = lane >> 4;
  float mh  = (hl == 0) ? m0 : (hl == 1) ? m1 : (hl == 2) ? m2 : m3;
  float dh  = (hl == 0) ? d0 : (hl == 1) ? d1 : (hl == 2) ? d2 : d3;
  float erh = (hl == 0) ? erd.x : (hl == 1) ? erd.y : (hl == 2) ? erd.z : erd.w;
  float inv = 1.0f / fmaxf(dh, 1e-9f);
  float a0 = 0, a1 = 0, a2 = 0, a3 = 0;
  for (int j = beg; j < end; ++j) {
    int s = st[j];
    float eh = lrelu(elt[(long)s * 4 + hl] + erh);
    float w = __expf(eh - mh) * inv;
    float4 zv = *(const float4*)(zt + (long)s * HIDDEN + lane * 4);
    a0 = fmaf(w, zv.x, a0);
    a1 = fmaf(w, zv.y, a1);
    a2 = fmaf(w, zv.z, a2);
    a3 = fmaf(w, zv.w, a3);
  }
  float4 bv = *(const float4*)(bias + t * HIDDEN + lane * 4);
  float4 o;
  o.x = fmaxf(a0 + bv.x, 0.f);
  o.y = fmaxf(a1 + bv.y, 0.f);
  o.z = fmaxf(a2 + bv.z, 0.f);
  o.w = fmaxf(a3 + bv.w, 0.f);
  *(float4*)(hout + (long)t * N_NODES * HIDDEN + (long)dst * HIDDEN + lane * 4) = o;
}

// ============================ GIN pre ============================
template <bool HASF>
__launch_bounds__(256)
__global__ void gin_pre_kernel(const float* __restrict__ h, const float* __restrict__ feats,
                               const int* __restrict__ row_ptr, const int* __restrict__ srcs,
                               const float* __restrict__ epsArr,
                               float* __restrict__ x, long strideX, int ldX) {
  int t = blockIdx.y;
  int wv = threadIdx.x >> 6, lane = threadIdx.x & 63;
  int dst = blockIdx.x * 4 + wv;
  if (dst >= N_NODES) return;
  const int* rp = row_ptr + t * (N_NODES + 1);
  int beg = rp[dst], end = rp[dst + 1];
  const float* ht = h + (long)t * N_NODES * HIDDEN;
  const int* st = srcs + (long)t * NEDGE;
  float ep = 1.0f + epsArr[t];
  float a0 = 0, a1 = 0, a2 = 0, a3 = 0, f0 = 0, f1 = 0;
  for (int j = beg; j < end; ++j) {
    int s = st[j];
    float4 hv = *(const float4*)(ht + (long)s * HIDDEN + lane * 4);
    a0 += hv.x; a1 += hv.y; a2 += hv.z; a3 += hv.w;
    if (HASF) {
      float2 fv = *(const float2*)(feats + (long)s * F_IN + lane * 2);
      f0 += fv.x; f1 += fv.y;
    }
  }
  float4 hs = *(const float4*)(ht + (long)dst * HIDDEN + lane * 4);
  float* xt = x + (long)t * strideX + (long)dst * ldX;
  float4 o;
  o.x = fmaf(ep, hs.x, a0);
  o.y = fmaf(ep, hs.y, a1);
  o.z = fmaf(ep, hs.z, a2);
  o.w = fmaf(ep, hs.w, a3);
  *(float4*)(xt + lane * 4) = o;
  if (HASF) {
    float2 fs = *(const float2*)(feats + (long)dst * F_IN + lane * 2);
    float2 of;
    of.x = fmaf(ep, fs.x, f0);
    of.y = fmaf(ep, fs.y, f1);
    *(float2*)(xt + HIDDEN + lane * 2) = of;
  }
}

// ============================ BN stats ============================
__launch_bounds__(256)
__global__ void stats_kernel(const float* __restrict__ y, long strideY,
                             float* __restrict__ sums) {
  int t = blockIdx.y;
  int col = threadIdx.x;
  int r0 = blockIdx.x * 512;
  const float* yt = y + (long)t * strideY;
  float s = 0, s2 = 0;
  int rend = min(r0 + 512, N_NODES);
  for (int r = r0; r < rend; ++r) {
    float v = yt[(long)r * HIDDEN + col];
    s += v;
    s2 = fmaf(v, v, s2);
  }
  atomicAdd(&sums[t * 2 * HIDDEN + col], s);
  atomicAdd(&sums[t * 2 * HIDDEN + HIDDEN + col], s2);
}

__global__ void bn_finalize_kernel(const float* __restrict__ sums,
                                   const float* __restrict__ g1, const float* __restrict__ be1,
                                   float* __restrict__ scale, float* __restrict__ shift) {
  int i = threadIdx.x + blockIdx.x * blockDim.x;
  if (i >= NTYPE * HIDDEN) return;
  int t = i / HIDDEN, c = i % HIDDEN;
  float mu  = sums[t * 2 * HIDDEN + c] * (1.0f / N_NODES);
  float ms  = sums[t * 2 * HIDDEN + HIDDEN + c] * (1.0f / N_NODES);
  float var = ms - mu * mu;
  float sc = g1[i] * rsqrtf(var + 1e-5f);
  scale[i] = sc;
  shift[i] = be1[i] - mu * sc;
}

// ============================ launch ============================
extern "C" void kernel_launch(void* const* d_in, const int* in_sizes, int n_in,
                              void* d_out, int out_size, void* d_ws, size_t ws_size,
                              hipStream_t stream) {
  const float* feats   = (const float*)d_in[0];
  const int* src0      = (const int*)d_in[1];
  const int* dst0      = (const int*)d_in[2];
  const int* src1      = (const int*)d_in[3];
  const int* dst1      = (const int*)d_in[4];
  const float* gat0_W  = (const float*)d_in[5];
  const float* gat0_al = (const float*)d_in[6];
  const float* gat0_ar = (const float*)d_in[7];
  const float* gat0_b  = (const float*)d_in[8];
  const float* gat1_W  = (const float*)d_in[9];
  const float* gat1_al = (const float*)d_in[10];
  const float* gat1_ar = (const float*)d_in[11];
  const float* gat1_b  = (const float*)d_in[12];
  const float* gin0_eps = (const float*)d_in[13];
  const float* gin0_W1  = (const float*)d_in[14];
  const float* gin0_b1  = (const float*)d_in[15];
  const float* gin0_g1  = (const float*)d_in[16];
  const float* gin0_be1 = (const float*)d_in[17];
  const float* gin0_W2  = (const float*)d_in[18];
  const float* gin0_b2  = (const float*)d_in[19];
  const float* gin1_eps = (const float*)d_in[20];
  const float* gin1_W1  = (const float*)d_in[21];
  const float* gin1_b1  = (const float*)d_in[22];
  const float* gin1_g1  = (const float*)d_in[23];
  const float* gin1_be1 = (const float*)d_in[24];
  const float* gin1_W2  = (const float*)d_in[25];
  const float* gin1_b2  = (const float*)d_in[26];
  float* out = (float*)d_out;

  char* p = (char*)d_ws;
  size_t off = 0;
  auto take = [&](size_t bytes) -> void* {
    void* r = p + off;
    off = (off + bytes + 255) & ~(size_t)255;
    return r;
  };
  float* bufA = (float*)take((size_t)NTYPE * N_NODES * 384 * 4);
  float* bufB = (float*)take((size_t)NTYPE * N_NODES * HIDDEN * 4);
  float* bufC = (float*)take((size_t)NTYPE * N_NODES * HIDDEN * 4);
  float* el   = (float*)take((size_t)NTYPE * N_NODES * 4 * 4);
  float* er   = (float*)take((size_t)NTYPE * N_NODES * 4 * 4);
  int* counts  = (int*)take((size_t)NTYPE * N_NODES * 4);
  int* row_ptr = (int*)take((size_t)NTYPE * (N_NODES + 1) * 4);
  int* cursor  = (int*)take((size_t)NTYPE * N_NODES * 4);
  int* srcs    = (int*)take((size_t)NTYPE * NEDGE * 4);
  float* bn_sums  = (float*)take((size_t)NTYPE * 2 * HIDDEN * 4);
  float* bn_scale = (float*)take((size_t)NTYPE * HIDDEN * 4);
  float* bn_shift = (float*)take((size_t)NTYPE * HIDDEN * 4);
  // bf16 hi/lo pre-transposed weights [T][256][K]
  u16* bh_g0   = (u16*)take((size_t)NTYPE * 256 * 128 * 2);
  u16* bl_g0   = (u16*)take((size_t)NTYPE * 256 * 128 * 2);
  u16* bh_g1   = (u16*)take((size_t)NTYPE * 256 * 256 * 2);
  u16* bl_g1   = (u16*)take((size_t)NTYPE * 256 * 256 * 2);
  u16* bh_i0w1 = (u16*)take((size_t)NTYPE * 256 * 384 * 2);
  u16* bl_i0w1 = (u16*)take((size_t)NTYPE * 256 * 384 * 2);
  u16* bh_i0w2 = (u16*)take((size_t)NTYPE * 256 * 256 * 2);
  u16* bl_i0w2 = (u16*)take((size_t)NTYPE * 256 * 256 * 2);
  u16* bh_i1w1 = (u16*)take((size_t)NTYPE * 256 * 256 * 2);
  u16* bl_i1w1 = (u16*)take((size_t)NTYPE * 256 * 256 * 2);
  u16* bh_i1w2 = (u16*)take((size_t)NTYPE * 256 * 256 * 2);
  u16* bl_i1w2 = (u16*)take((size_t)NTYPE * 256 * 256 * 2);
  (void)ws_size; (void)in_sizes; (void)n_in; (void)out_size;

  const dim3 blk(256);
  const int egrid = (NEDGE + 255) / 256;
  const dim3 ggrid((N_NODES + 127) / 128, 2, NTYPE);
  const dim3 agrid((N_NODES + 3) / 4, NTYPE);
  const size_t elersz = 2 * (size_t)NTYPE * N_NODES * 4 * sizeof(float);
  const long sN256 = (long)N_NODES * HIDDEN;

  // ---- weight prep (runs every call; inputs restored pre-launch) ----
  prep_b_kernel<<<dim3(2, 4, NTYPE), blk, 0, stream>>>(gat0_W, bh_g0, bl_g0, 128);
  prep_b_kernel<<<dim3(4, 4, NTYPE), blk, 0, stream>>>(gat1_W, bh_g1, bl_g1, 256);
  prep_b_kernel<<<dim3(6, 4, NTYPE), blk, 0, stream>>>(gin0_W1, bh_i0w1, bl_i0w1, 384);
  prep_b_kernel<<<dim3(4, 4, NTYPE), blk, 0, stream>>>(gin0_W2, bh_i0w2, bl_i0w2, 256);
  prep_b_kernel<<<dim3(4, 4, NTYPE), blk, 0, stream>>>(gin1_W1, bh_i1w1, bl_i1w1, 256);
  prep_b_kernel<<<dim3(4, 4, NTYPE), blk, 0, stream>>>(gin1_W2, bh_i1w2, bl_i1w2, 256);

  // ---- CSR build ----
  hipMemsetAsync(counts, 0, (size_t)NTYPE * N_NODES * 4, stream);
  hist_kernel<<<dim3(egrid, NTYPE), blk, 0, stream>>>(dst0, dst1, counts);
  scan_kernel<<<NTYPE, 1024, 0, stream>>>(counts, row_ptr, cursor);
  scatter_kernel<<<dim3(egrid, NTYPE), blk, 0, stream>>>(src0, dst0, src1, dst1, cursor, srcs);

  // ---- GAT layer 0 (K=128, A = feats shared across types) ----
  hipMemsetAsync(el, 0, elersz, stream);
  gemm_mfma<0><<<ggrid, blk, 0, stream>>>(feats, 0L, F_IN, F_IN, bh_g0, bl_g0, nullptr,
      bufB, sN256, HIDDEN, 0, gat0_al, gat0_ar, el, er, nullptr, nullptr, N_NODES);
  gat_agg_kernel<<<agrid, blk, 0, stream>>>(bufB, el, er, row_ptr, srcs, gat0_b, bufC);

  // ---- GAT layer 1 (K=256) ----
  hipMemsetAsync(el, 0, elersz, stream);
  gemm_mfma<0><<<ggrid, blk, 0, stream>>>(bufC, sN256, HIDDEN, HIDDEN, bh_g1, bl_g1, nullptr,
      bufB, sN256, HIDDEN, 0, gat1_al, gat1_ar, el, er, nullptr, nullptr, N_NODES);
  gat_agg_kernel<<<agrid, blk, 0, stream>>>(bufB, el, er, row_ptr, srcs, gat1_b, bufC);

  // ---- GIN layer 0 (skip-concat, K=384) ----
  gin_pre_kernel<true><<<agrid, blk, 0, stream>>>(bufC, feats, row_ptr, srcs, gin0_eps,
      bufA, (long)N_NODES * 384, 384);
  hipMemsetAsync(bn_sums, 0, (size_t)NTYPE * 2 * HIDDEN * 4, stream);
  gemm_mfma<1><<<ggrid, blk, 0, stream>>>(bufA, (long)N_NODES * 384, 384, 384, bh_i0w1, bl_i0w1,
      gin0_b1, bufB, sN256, HIDDEN, 0, nullptr, nullptr, nullptr, nullptr, nullptr, nullptr, N_NODES);
  stats_kernel<<<dim3((N_NODES + 511) / 512, NTYPE), blk, 0, stream>>>(bufB, sN256, bn_sums);
  bn_finalize_kernel<<<1, NTYPE * HIDDEN, 0, stream>>>(bn_sums, gin0_g1, gin0_be1, bn_scale, bn_shift);
  gemm_mfma<2><<<ggrid, blk, 0, stream>>>(bufB, sN256, HIDDEN, HIDDEN, bh_i0w2, bl_i0w2,
      gin0_b2, bufC, sN256, HIDDEN, 0, nullptr, nullptr, nullptr, nullptr, bn_scale, bn_shift, N_NODES);

  // ---- GIN layer 1 (K=256) ----
  gin_pre_kernel<false><<<agrid, blk, 0, stream>>>(bufC, nullptr, row_ptr, srcs, gin1_eps,
      bufA, sN256, HIDDEN);
  hipMemsetAsync(bn_sums, 0, (size_t)NTYPE * 2 * HIDDEN * 4, stream);
  gemm_mfma<1><<<ggrid, blk, 0, stream>>>(bufA, sN256, HIDDEN, HIDDEN, bh_i1w1, bl_i1w1,
      gin1_b1, bufB, sN256, HIDDEN, 0, nullptr, nullptr, nullptr, nullptr, nullptr, nullptr, N_NODES);
  stats_kernel<<<dim3((N_NODES + 511) / 512, NTYPE), blk, 0, stream>>>(bufB, sN256, bn_sums);
  bn_finalize_kernel<<<1, NTYPE * HIDDEN, 0, stream>>>(bn_sums, gin1_g1, gin1_be1, bn_scale, bn_shift);
  // final: write straight into d_out[N, 512] at column offset t*256
  gemm_mfma<2><<<ggrid, blk, 0, stream>>>(bufB, sN256, HIDDEN, HIDDEN, bh_i1w2, bl_i1w2,
      gin1_b2, out, 0L, NTYPE * HIDDEN, HIDDEN, nullptr, nullptr, nullptr, nullptr, bn_scale, bn_shift, N_NODES);
}

// Round 4
// 1873.266 us; speedup vs baseline: 1.2399x; 1.0416x over previous
//
#include <hip/hip_runtime.h>
#include <math.h>
#include <cstdint>

#define N_NODES 50000
#define F_IN    128
#define HIDDEN  256
#define NHEAD   4
#define HEADD   64
#define NEDGE   400000
#define NTYPE   2

typedef unsigned short u16;
typedef float f32x4 __attribute__((ext_vector_type(4)));
typedef short s16x8 __attribute__((ext_vector_type(8)));

__device__ __forceinline__ float lrelu(float x) { return x > 0.f ? x : 0.2f * x; }

__device__ __forceinline__ void bsplit(float f, u16& hi, u16& lo) {
  unsigned u = __float_as_uint(f);
  hi = (u16)(u >> 16);
  float r = f - __uint_as_float(u & 0xffff0000u);
  lo = (u16)(__float_as_uint(r) >> 16);
}

__device__ __forceinline__ void gl_lds16(const void* g, void* l) {
  __builtin_amdgcn_global_load_lds(
      (const __attribute__((address_space(1))) void*)g,
      (__attribute__((address_space(3))) void*)l, 16, 0, 0);
}

// ============================ CSR build ============================
__global__ void hist_kernel(const int* __restrict__ dst0, const int* __restrict__ dst1,
                            int* __restrict__ counts) {
  int t = blockIdx.y;
  int e = blockIdx.x * blockDim.x + threadIdx.x;
  if (e >= NEDGE) return;
  const int* dst = t ? dst1 : dst0;
  atomicAdd(&counts[t * N_NODES + dst[e]], 1);
}

__launch_bounds__(1024)
__global__ void scan_kernel(const int* __restrict__ counts, int* __restrict__ row_ptr,
                            int* __restrict__ cursor) {
  int t = blockIdx.x;
  int tid = threadIdx.x;
  int lane = tid & 63, wv = tid >> 6;  // 16 waves
  __shared__ int wsum[16];
  int carry = 0;
  for (int base = 0; base < N_NODES; base += 1024) {
    int i = base + tid;
    int v = (i < N_NODES) ? counts[t * N_NODES + i] : 0;
    int x = v;
#pragma unroll
    for (int off = 1; off < 64; off <<= 1) {
      int u = __shfl_up(x, off);
      if (lane >= off) x += u;
    }
    if (lane == 63) wsum[wv] = x;
    __syncthreads();
    if (wv == 0 && lane < 16) {
      int y = wsum[lane];
#pragma unroll
      for (int off = 1; off < 16; off <<= 1) {
        int u = __shfl_up(y, off);
        if (lane >= off) y += u;
      }
      wsum[lane] = y;
    }
    __syncthreads();
    int blockoff = wv ? wsum[wv - 1] : 0;
    int tot = wsum[15];
    int excl = carry + blockoff + x - v;
    if (i < N_NODES) {
      row_ptr[t * (N_NODES + 1) + i] = excl;
      cursor[t * N_NODES + i] = excl;
    }
    carry += tot;
    __syncthreads();
  }
  if (tid == 0) row_ptr[t * (N_NODES + 1) + N_NODES] = carry;
}

__global__ void scatter_kernel(const int* __restrict__ src0, const int* __restrict__ dst0,
                               const int* __restrict__ src1, const int* __restrict__ dst1,
                               int* __restrict__ cursor, int* __restrict__ srcs) {
  int t = blockIdx.y;
  int e = blockIdx.x * blockDim.x + threadIdx.x;
  if (e >= NEDGE) return;
  const int* src = t ? src1 : src0;
  const int* dst = t ? dst1 : dst0;
  int d = dst[e];
  int pos = atomicAdd(&cursor[t * N_NODES + d], 1);
  srcs[t * NEDGE + pos] = src[e];
}

// ============================ prep: feats fp32 -> bf16 hi/lo ============================
__global__ void prep_feats_kernel(const float* __restrict__ f, u16* __restrict__ fh,
                                  u16* __restrict__ fl) {
  long i = ((long)blockIdx.x * blockDim.x + threadIdx.x) * 4;
  if (i >= (long)N_NODES * F_IN) return;
  float4 v = *(const float4*)(f + i);
  ushort4 hi, lo;
  bsplit(v.x, hi.x, lo.x);
  bsplit(v.y, hi.y, lo.y);
  bsplit(v.z, hi.z, lo.z);
  bsplit(v.w, hi.w, lo.w);
  *(ushort4*)(fh + i) = hi;
  *(ushort4*)(fl + i) = lo;
}

// ============================ weight prep: transpose + bf16 hi/lo split ============================
// W[t][K][256] fp32  ->  Bth/Btl[t][256][K] bf16
__launch_bounds__(256)
__global__ void prep_b_kernel(const float* __restrict__ W, u16* __restrict__ bth,
                              u16* __restrict__ btl, int K) {
  __shared__ unsigned tile[64][65];
  const int kt = blockIdx.x * 64, nt = blockIdx.y * 64, t = blockIdx.z;
  const int tid = threadIdx.x;
  const float* Wt = W + (size_t)t * K * 256;
  {
    int k = tid >> 2;
    int ncl = (tid & 3) * 16;
#pragma unroll
    for (int q = 0; q < 4; ++q) {
      float4 v = *(const float4*)(Wt + (size_t)(kt + k) * 256 + nt + ncl + q * 4);
      float f[4] = {v.x, v.y, v.z, v.w};
#pragma unroll
      for (int e = 0; e < 4; ++e) {
        u16 hi, lo;
        bsplit(f[e], hi, lo);
        tile[k][ncl + q * 4 + e] = (unsigned)hi | ((unsigned)lo << 16);
      }
    }
  }
  __syncthreads();
  {
    int n = tid & 63;
    int kc = (tid >> 6) * 16;
    u16 hi16[16], lo16[16];
#pragma unroll
    for (int i = 0; i < 16; ++i) {
      unsigned u = tile[kc + i][n];
      hi16[i] = (u16)(u & 0xffff);
      lo16[i] = (u16)(u >> 16);
    }
    size_t ob = ((size_t)t * 256 + nt + n) * K + kt + kc;
    *(s16x8*)(bth + ob)     = *(s16x8*)&hi16[0];
    *(s16x8*)(bth + ob + 8) = *(s16x8*)&hi16[8];
    *(s16x8*)(btl + ob)     = *(s16x8*)&lo16[0];
    *(s16x8*)(btl + ob + 8) = *(s16x8*)&lo16[8];
  }
}

// ============================ MFMA GEMM (bf16 3-term split) ============================
// MODE 0: GAT  — write z fp32; fused el/er (plain stores, single writer per slot)
// MODE 1: plain — write acc fp32 (P = A@W, no bias)
// MODE 2: A = fp32 with BN scale/shift + relu transform; out = relu(acc + bias)
// ASPLIT: A given as pre-split bf16 hi/lo (1 or 2 K-sources), staged via global_load_lds
// OSPLIT: epilogue writes bf16 hi/lo pair instead of fp32
// Tile BM=128,BN=128,BK=64; 4 waves (2x2), 64x64 per wave.
// LDS chunk-major: plane c (k-chunk of 8) stride 2048B, row stride 16B — conflict-free,
// and linear in lane order so global_load_lds (wave-uniform dest + lane*16) works.
template <int MODE, bool ASPLIT, bool OSPLIT>
__launch_bounds__(256)
__global__ void gemm_mfma(const float* __restrict__ Af,
                          const u16* __restrict__ A1h, const u16* __restrict__ A1l,
                          long strideA1, int ldA1, int KA1,
                          const u16* __restrict__ A2h, const u16* __restrict__ A2l,
                          long strideA2, int ldA2,
                          long strideAf, int K,
                          const u16* __restrict__ Bth, const u16* __restrict__ Btl,
                          const float* __restrict__ bias,
                          float* __restrict__ Cf, u16* __restrict__ Ch, u16* __restrict__ Cl,
                          long strideC, int ldC, int colOffT,
                          const float* __restrict__ al, const float* __restrict__ arv,
                          float* __restrict__ el, float* __restrict__ er,
                          const float* __restrict__ bnscale, const float* __restrict__ bnshift,
                          int M) {
  __shared__ __align__(16) char lds[65536];
  char* Ah = lds;
  char* Al = lds + 16384;
  char* Bh = lds + 32768;
  char* Bl = lds + 49152;

  const int t  = blockIdx.z;
  const int m0 = blockIdx.x * 128;
  const int n0 = blockIdx.y * 128;
  const int tid = threadIdx.x;
  const int lane = tid & 63;
  const int wid = tid >> 6;
  const int wm = wid >> 1, wn = wid & 1;
  const int lm = lane & 15, lg = lane >> 4;

  f32x4 acc[4][4];
#pragma unroll
  for (int i = 0; i < 4; ++i)
#pragma unroll
    for (int j = 0; j < 4; ++j) acc[i][j] = (f32x4)(0.f);

  // reg-staging assignment (MODE 2 only)
  const int ar2 = tid >> 1, akh = tid & 1;
  const bool avalid = (m0 + ar2) < M;
  const float* bsc = (MODE == 2) ? bnscale + (long)t * K : nullptr;
  const float* bsh = (MODE == 2) ? bnshift + (long)t * K : nullptr;

  for (int k0 = 0; k0 < K; k0 += 64) {
    if (k0) __syncthreads();
    if (ASPLIT) {
      // ---- A + B staging fully via global_load_lds (16 loads/wave) ----
#pragma unroll
      for (int q = 0; q < 8; ++q) {
        int v = wid * 8 + q;  // 0..31
        int c = (v >> 1) & 7, half = v & 1;
        bool hibuf = v < 16;
        // A
        int rowA = m0 + half * 64 + lane;
        if (rowA > M - 1) rowA = M - 1;
        const u16* ga;
        if (k0 < KA1)
          ga = (hibuf ? A1h : A1l) + (long)t * strideA1 + (long)rowA * ldA1 + k0 + c * 8;
        else
          ga = (hibuf ? A2h : A2l) + (long)t * strideA2 + (long)rowA * ldA2 + (k0 - KA1) + c * 8;
        gl_lds16(ga, (hibuf ? Ah : Al) + c * 2048 + half * 1024);
        // B
        int n = n0 + half * 64 + lane;
        const u16* gb = (hibuf ? Bth : Btl) + ((size_t)t * 256 + n) * K + k0 + c * 8;
        gl_lds16(gb, (hibuf ? Bh : Bl) + c * 2048 + half * 1024);
      }
    } else {
      // ---- B via global_load_lds (8 loads/wave) ----
#pragma unroll
      for (int q = 0; q < 8; ++q) {
        int v = wid * 8 + q;
        int c = (v >> 1) & 7, half = v & 1;
        bool hibuf = v < 16;
        int n = n0 + half * 64 + lane;
        const u16* gb = (hibuf ? Bth : Btl) + ((size_t)t * 256 + n) * K + k0 + c * 8;
        gl_lds16(gb, (hibuf ? Bh : Bl) + c * 2048 + half * 1024);
      }
      // ---- A: fp32 load + BN transform + split + ds_write ----
      float fv[32];
      const float* ap = Af + (long)t * strideAf + (long)(m0 + ar2) * ldA1 + k0 + akh * 32;
#pragma unroll
      for (int q = 0; q < 8; ++q) {
        float4 v = make_float4(0.f, 0.f, 0.f, 0.f);
        if (avalid) {
          v = *(const float4*)(ap + q * 4);
          if (MODE == 2) {
            int kb = k0 + akh * 32 + q * 4;
            float4 sc = *(const float4*)(bsc + kb);
            float4 sh = *(const float4*)(bsh + kb);
            v.x = fmaxf(fmaf(v.x, sc.x, sh.x), 0.f);
            v.y = fmaxf(fmaf(v.y, sc.y, sh.y), 0.f);
            v.z = fmaxf(fmaf(v.z, sc.z, sh.z), 0.f);
            v.w = fmaxf(fmaf(v.w, sc.w, sh.w), 0.f);
          }
        }
        fv[q * 4 + 0] = v.x; fv[q * 4 + 1] = v.y; fv[q * 4 + 2] = v.z; fv[q * 4 + 3] = v.w;
      }
#pragma unroll
      for (int cl_ = 0; cl_ < 4; ++cl_) {
        u16 hi[8], lo[8];
#pragma unroll
        for (int e = 0; e < 8; ++e) bsplit(fv[cl_ * 8 + e], hi[e], lo[e]);
        int off = (akh * 4 + cl_) * 2048 + ar2 * 16;
        *(s16x8*)(Ah + off) = *(s16x8*)&hi[0];
        *(s16x8*)(Al + off) = *(s16x8*)&lo[0];
      }
    }
    __syncthreads();
    // ---- MFMA ----
#pragma unroll
    for (int kk = 0; kk < 2; ++kk) {
      int c = kk * 4 + lg;
      s16x8 fAh[4], fAl[4], fBh[4], fBl[4];
#pragma unroll
      for (int i = 0; i < 4; ++i) {
        int off = c * 2048 + (wm * 64 + i * 16 + lm) * 16;
        fAh[i] = *(const s16x8*)(Ah + off);
        fAl[i] = *(const s16x8*)(Al + off);
      }
#pragma unroll
      for (int j = 0; j < 4; ++j) {
        int off = c * 2048 + (wn * 64 + j * 16 + lm) * 16;
        fBh[j] = *(const s16x8*)(Bh + off);
        fBl[j] = *(const s16x8*)(Bl + off);
      }
#pragma unroll
      for (int i = 0; i < 4; ++i)
#pragma unroll
        for (int j = 0; j < 4; ++j) {
          acc[i][j] = __builtin_amdgcn_mfma_f32_16x16x32_bf16(fAh[i], fBh[j], acc[i][j], 0, 0, 0);
          acc[i][j] = __builtin_amdgcn_mfma_f32_16x16x32_bf16(fAh[i], fBl[j], acc[i][j], 0, 0, 0);
          acc[i][j] = __builtin_amdgcn_mfma_f32_16x16x32_bf16(fAl[i], fBh[j], acc[i][j], 0, 0, 0);
        }
    }
  }

  // ---- epilogue ----
  if (MODE == 0) {
    const float* alt = al + t * HIDDEN;
    const float* art = arv + t * HIDDEN;
    const int head = (n0 + wn * 64) >> 6;
    float av[4], rv[4];
#pragma unroll
    for (int j = 0; j < 4; ++j) {
      int gc = n0 + wn * 64 + j * 16 + lm;
      av[j] = alt[gc];
      rv[j] = art[gc];
    }
#pragma unroll
    for (int i = 0; i < 4; ++i)
#pragma unroll
      for (int r = 0; r < 4; ++r) {
        float pel = 0.f, per = 0.f;
#pragma unroll
        for (int j = 0; j < 4; ++j) {
          pel = fmaf(acc[i][j][r], av[j], pel);
          per = fmaf(acc[i][j][r], rv[j], per);
        }
#pragma unroll
        for (int o = 1; o < 16; o <<= 1) {
          pel += __shfl_xor(pel, o);
          per += __shfl_xor(per, o);
        }
        int row = m0 + wm * 64 + i * 16 + lg * 4 + r;
        if (lm == 0 && row < M) {
          el[((long)t * N_NODES + row) * 4 + head] = pel;  // single writer
          er[((long)t * N_NODES + row) * 4 + head] = per;
        }
      }
  }

  float bv[4];
  if (MODE == 2) {
#pragma unroll
    for (int j = 0; j < 4; ++j) bv[j] = bias[t * HIDDEN + n0 + wn * 64 + j * 16 + lm];
  }
  const int colOff = colOffT * t;
#pragma unroll
  for (int i = 0; i < 4; ++i)
#pragma unroll
    for (int r = 0; r < 4; ++r) {
      int row = m0 + wm * 64 + i * 16 + lg * 4 + r;
      if (row < M) {
#pragma unroll
        for (int j = 0; j < 4; ++j) {
          int col = n0 + wn * 64 + j * 16 + lm;
          float v = acc[i][j][r];
          if (MODE == 2) v = fmaxf(v + bv[j], 0.f);
          if (OSPLIT) {
            u16 hi, lo;
            bsplit(v, hi, lo);
            Ch[(long)t * strideC + (long)row * ldC + col] = hi;
            Cl[(long)t * strideC + (long)row * ldC + col] = lo;
          } else {
            Cf[(long)t * strideC + colOff + (long)row * ldC + col] = v;
          }
        }
      }
    }
}

// ============================ GAT aggregation (out: bf16 hi/lo) ============================
__launch_bounds__(256)
__global__ void gat_agg_kernel(const float* __restrict__ z, const float* __restrict__ el,
                               const float* __restrict__ er, const int* __restrict__ row_ptr,
                               const int* __restrict__ srcs, const float* __restrict__ bias,
                               u16* __restrict__ Hh, u16* __restrict__ Hl) {
  int t = blockIdx.y;
  int wv = threadIdx.x >> 6, lane = threadIdx.x & 63;
  int dst = blockIdx.x * 4 + wv;
  if (dst >= N_NODES) return;
  const int* rp = row_ptr + t * (N_NODES + 1);
  int beg = rp[dst], end = rp[dst + 1];
  const float* elt = el + (long)t * N_NODES * 4;
  const float* zt  = z + (long)t * N_NODES * HIDDEN;
  const int* st = srcs + (long)t * NEDGE;
  float4 erd = *(const float4*)(er + (long)t * N_NODES * 4 + (long)dst * 4);

  float m0 = -INFINITY, m1 = -INFINITY, m2 = -INFINITY, m3 = -INFINITY;
  for (int j = beg + lane; j < end; j += 64) {
    int s = st[j];
    float4 ev = *(const float4*)(elt + (long)s * 4);
    m0 = fmaxf(m0, lrelu(ev.x + erd.x));
    m1 = fmaxf(m1, lrelu(ev.y + erd.y));
    m2 = fmaxf(m2, lrelu(ev.z + erd.z));
    m3 = fmaxf(m3, lrelu(ev.w + erd.w));
  }
#pragma unroll
  for (int off = 32; off; off >>= 1) {
    m0 = fmaxf(m0, __shfl_xor(m0, off));
    m1 = fmaxf(m1, __shfl_xor(m1, off));
    m2 = fmaxf(m2, __shfl_xor(m2, off));
    m3 = fmaxf(m3, __shfl_xor(m3, off));
  }
  float d0 = 0, d1 = 0, d2 = 0, d3 = 0;
  for (int j = beg + lane; j < end; j += 64) {
    int s = st[j];
    float4 ev = *(const float4*)(elt + (long)s * 4);
    d0 += __expf(lrelu(ev.x + erd.x) - m0);
    d1 += __expf(lrelu(ev.y + erd.y) - m1);
    d2 += __expf(lrelu(ev.z + erd.z) - m2);
    d3 += __expf(lrelu(ev.w + erd.w) - m3);
  }
#pragma unroll
  for (int off = 32; off; off >>= 1) {
    d0 += __shfl_xor(d0, off);
    d1 += __shfl_xor(d1, off);
    d2 += __shfl_xor(d2, off);
    d3 += __shfl_xor(d3, off);
  }
  int hl = lane >> 4;
  float mh  = (hl == 0) ? m0 : (hl == 1) ? m1 : (hl == 2) ? m2 : m3;
  float dh  = (hl == 0) ? d0 : (hl == 1) ? d1 : (hl == 2) ? d2 : d3;
  float erh = (hl == 0) ? erd.x : (hl == 1) ? erd.y : (hl == 2) ? erd.z : erd.w;
  float inv = 1.0f / fmaxf(dh, 1e-9f);
  float a0 = 0, a1 = 0, a2 = 0, a3 = 0;
  for (int j = beg; j < end; ++j) {
    int s = st[j];
    float eh = lrelu(elt[(long)s * 4 + hl] + erh);
    float w = __expf(eh - mh) * inv;
    float4 zv = *(const float4*)(zt + (long)s * HIDDEN + lane * 4);
    a0 = fmaf(w, zv.x, a0);
    a1 = fmaf(w, zv.y, a1);
    a2 = fmaf(w, zv.z, a2);
    a3 = fmaf(w, zv.w, a3);
  }
  float4 bv = *(const float4*)(bias + t * HIDDEN + lane * 4);
  float o0 = fmaxf(a0 + bv.x, 0.f);
  float o1 = fmaxf(a1 + bv.y, 0.f);
  float o2 = fmaxf(a2 + bv.z, 0.f);
  float o3 = fmaxf(a3 + bv.w, 0.f);
  ushort4 hi, lo;
  bsplit(o0, hi.x, lo.x);
  bsplit(o1, hi.y, lo.y);
  bsplit(o2, hi.z, lo.z);
  bsplit(o3, hi.w, lo.w);
  long ob = (long)t * N_NODES * HIDDEN + (long)dst * HIDDEN + lane * 4;
  *(ushort4*)(Hh + ob) = hi;
  *(ushort4*)(Hl + ob) = lo;
}

// ============================ GIN aggregation on P ============================
// y = (1+eps)*P[dst] + sum_{src} P[src] + b1
__launch_bounds__(256)
__global__ void gin_agg_kernel(const float* __restrict__ P, const int* __restrict__ row_ptr,
                               const int* __restrict__ srcs, const float* __restrict__ epsArr,
                               const float* __restrict__ b1, float* __restrict__ y) {
  int t = blockIdx.y;
  int wv = threadIdx.x >> 6, lane = threadIdx.x & 63;
  int dst = blockIdx.x * 4 + wv;
  if (dst >= N_NODES) return;
  const int* rp = row_ptr + t * (N_NODES + 1);
  int beg = rp[dst], end = rp[dst + 1];
  const float* Pt = P + (long)t * N_NODES * HIDDEN;
  const int* st = srcs + (long)t * NEDGE;
  float ep = 1.0f + epsArr[t];
  float a0 = 0, a1 = 0, a2 = 0, a3 = 0;
  for (int j = beg; j < end; ++j) {
    int s = st[j];
    float4 pv = *(const float4*)(Pt + (long)s * HIDDEN + lane * 4);
    a0 += pv.x; a1 += pv.y; a2 += pv.z; a3 += pv.w;
  }
  float4 ps = *(const float4*)(Pt + (long)dst * HIDDEN + lane * 4);
  float4 bb = *(const float4*)(b1 + t * HIDDEN + lane * 4);
  float4 o;
  o.x = fmaf(ep, ps.x, a0) + bb.x;
  o.y = fmaf(ep, ps.y, a1) + bb.y;
  o.z = fmaf(ep, ps.z, a2) + bb.z;
  o.w = fmaf(ep, ps.w, a3) + bb.w;
  *(float4*)(y + (long)t * N_NODES * HIDDEN + (long)dst * HIDDEN + lane * 4) = o;
}

// ============================ BN stats ============================
__launch_bounds__(256)
__global__ void stats_kernel(const float* __restrict__ y, long strideY,
                             float* __restrict__ sums) {
  int t = blockIdx.y;
  int col = threadIdx.x;
  int r0 = blockIdx.x * 512;
  const float* yt = y + (long)t * strideY;
  float s = 0, s2 = 0;
  int rend = min(r0 + 512, N_NODES);
  for (int r = r0; r < rend; ++r) {
    float v = yt[(long)r * HIDDEN + col];
    s += v;
    s2 = fmaf(v, v, s2);
  }
  atomicAdd(&sums[t * 2 * HIDDEN + col], s);
  atomicAdd(&sums[t * 2 * HIDDEN + HIDDEN + col], s2);
}

__global__ void bn_finalize_kernel(const float* __restrict__ sums,
                                   const float* __restrict__ g1, const float* __restrict__ be1,
                                   float* __restrict__ scale, float* __restrict__ shift) {
  int i = threadIdx.x + blockIdx.x * blockDim.x;
  if (i >= NTYPE * HIDDEN) return;
  float mu  = sums[(i / HIDDEN) * 2 * HIDDEN + (i % HIDDEN)] * (1.0f / N_NODES);
  float ms  = sums[(i / HIDDEN) * 2 * HIDDEN + HIDDEN + (i % HIDDEN)] * (1.0f / N_NODES);
  float var = ms - mu * mu;
  float sc = g1[i] * rsqrtf(var + 1e-5f);
  scale[i] = sc;
  shift[i] = be1[i] - mu * sc;
}

// ============================ launch ============================
extern "C" void kernel_launch(void* const* d_in, const int* in_sizes, int n_in,
                              void* d_out, int out_size, void* d_ws, size_t ws_size,
                              hipStream_t stream) {
  const float* feats   = (const float*)d_in[0];
  const int* src0      = (const int*)d_in[1];
  const int* dst0      = (const int*)d_in[2];
  const int* src1      = (const int*)d_in[3];
  const int* dst1      = (const int*)d_in[4];
  const float* gat0_W  = (const float*)d_in[5];
  const float* gat0_al = (const float*)d_in[6];
  const float* gat0_ar = (const float*)d_in[7];
  const float* gat0_b  = (const float*)d_in[8];
  const float* gat1_W  = (const float*)d_in[9];
  const float* gat1_al = (const float*)d_in[10];
  const float* gat1_ar = (const float*)d_in[11];
  const float* gat1_b  = (const float*)d_in[12];
  const float* gin0_eps = (const float*)d_in[13];
  const float* gin0_W1  = (const float*)d_in[14];
  const float* gin0_b1  = (const float*)d_in[15];
  const float* gin0_g1  = (const float*)d_in[16];
  const float* gin0_be1 = (const float*)d_in[17];
  const float* gin0_W2  = (const float*)d_in[18];
  const float* gin0_b2  = (const float*)d_in[19];
  const float* gin1_eps = (const float*)d_in[20];
  const float* gin1_W1  = (const float*)d_in[21];
  const float* gin1_b1  = (const float*)d_in[22];
  const float* gin1_g1  = (const float*)d_in[23];
  const float* gin1_be1 = (const float*)d_in[24];
  const float* gin1_W2  = (const float*)d_in[25];
  const float* gin1_b2  = (const float*)d_in[26];
  float* out = (float*)d_out;

  char* p = (char*)d_ws;
  size_t off = 0;
  auto take = [&](size_t bytes) -> void* {
    void* r = p + off;
    off = (off + bytes + 255) & ~(size_t)255;
    return r;
  };
  float* bufA  = (float*)take((size_t)NTYPE * N_NODES * HIDDEN * 4);  // y
  float* bufB  = (float*)take((size_t)NTYPE * N_NODES * HIDDEN * 4);  // z / P
  u16*   bufCh = (u16*)take((size_t)NTYPE * N_NODES * HIDDEN * 2);    // h hi
  u16*   bufCl = (u16*)take((size_t)NTYPE * N_NODES * HIDDEN * 2);    // h lo
  u16*   fhi   = (u16*)take((size_t)N_NODES * F_IN * 2);
  u16*   flo   = (u16*)take((size_t)N_NODES * F_IN * 2);
  float* el   = (float*)take((size_t)NTYPE * N_NODES * 4 * 4);
  float* er   = (float*)take((size_t)NTYPE * N_NODES * 4 * 4);
  int* counts  = (int*)take((size_t)NTYPE * N_NODES * 4);
  int* row_ptr = (int*)take((size_t)NTYPE * (N_NODES + 1) * 4);
  int* cursor  = (int*)take((size_t)NTYPE * N_NODES * 4);
  int* srcs    = (int*)take((size_t)NTYPE * NEDGE * 4);
  float* bn_sums  = (float*)take((size_t)NTYPE * 2 * HIDDEN * 4);
  float* bn_scale = (float*)take((size_t)NTYPE * HIDDEN * 4);
  float* bn_shift = (float*)take((size_t)NTYPE * HIDDEN * 4);
  u16* bh_g0   = (u16*)take((size_t)NTYPE * 256 * 128 * 2);
  u16* bl_g0   = (u16*)take((size_t)NTYPE * 256 * 128 * 2);
  u16* bh_g1   = (u16*)take((size_t)NTYPE * 256 * 256 * 2);
  u16* bl_g1   = (u16*)take((size_t)NTYPE * 256 * 256 * 2);
  u16* bh_i0w1 = (u16*)take((size_t)NTYPE * 256 * 384 * 2);
  u16* bl_i0w1 = (u16*)take((size_t)NTYPE * 256 * 384 * 2);
  u16* bh_i0w2 = (u16*)take((size_t)NTYPE * 256 * 256 * 2);
  u16* bl_i0w2 = (u16*)take((size_t)NTYPE * 256 * 256 * 2);
  u16* bh_i1w1 = (u16*)take((size_t)NTYPE * 256 * 256 * 2);
  u16* bl_i1w1 = (u16*)take((size_t)NTYPE * 256 * 256 * 2);
  u16* bh_i1w2 = (u16*)take((size_t)NTYPE * 256 * 256 * 2);
  u16* bl_i1w2 = (u16*)take((size_t)NTYPE * 256 * 256 * 2);
  (void)ws_size; (void)in_sizes; (void)n_in; (void)out_size;

  const dim3 blk(256);
  const int egrid = (NEDGE + 255) / 256;
  const dim3 ggrid((N_NODES + 127) / 128, 2, NTYPE);
  const dim3 agrid((N_NODES + 3) / 4, NTYPE);
  const long sN256 = (long)N_NODES * HIDDEN;

  // ---- prep ----
  prep_feats_kernel<<<(N_NODES * F_IN / 4 + 255) / 256, blk, 0, stream>>>(feats, fhi, flo);
  prep_b_kernel<<<dim3(2, 4, NTYPE), blk, 0, stream>>>(gat0_W, bh_g0, bl_g0, 128);
  prep_b_kernel<<<dim3(4, 4, NTYPE), blk, 0, stream>>>(gat1_W, bh_g1, bl_g1, 256);
  prep_b_kernel<<<dim3(6, 4, NTYPE), blk, 0, stream>>>(gin0_W1, bh_i0w1, bl_i0w1, 384);
  prep_b_kernel<<<dim3(4, 4, NTYPE), blk, 0, stream>>>(gin0_W2, bh_i0w2, bl_i0w2, 256);
  prep_b_kernel<<<dim3(4, 4, NTYPE), blk, 0, stream>>>(gin1_W1, bh_i1w1, bl_i1w1, 256);
  prep_b_kernel<<<dim3(4, 4, NTYPE), blk, 0, stream>>>(gin1_W2, bh_i1w2, bl_i1w2, 256);

  // ---- CSR build ----
  hipMemsetAsync(counts, 0, (size_t)NTYPE * N_NODES * 4, stream);
  hist_kernel<<<dim3(egrid, NTYPE), blk, 0, stream>>>(dst0, dst1, counts);
  scan_kernel<<<NTYPE, 1024, 0, stream>>>(counts, row_ptr, cursor);
  scatter_kernel<<<dim3(egrid, NTYPE), blk, 0, stream>>>(src0, dst0, src1, dst1, cursor, srcs);

  // ---- GAT layer 0 ----
  gemm_mfma<0, true, false><<<ggrid, blk, 0, stream>>>(nullptr,
      fhi, flo, 0L, F_IN, F_IN, nullptr, nullptr, 0L, 0, 0L, F_IN,
      bh_g0, bl_g0, nullptr, bufB, nullptr, nullptr, sN256, HIDDEN, 0,
      gat0_al, gat0_ar, el, er, nullptr, nullptr, N_NODES);
  gat_agg_kernel<<<agrid, blk, 0, stream>>>(bufB, el, er, row_ptr, srcs, gat0_b, bufCh, bufCl);

  // ---- GAT layer 1 ----
  gemm_mfma<0, true, false><<<ggrid, blk, 0, stream>>>(nullptr,
      bufCh, bufCl, sN256, HIDDEN, HIDDEN, nullptr, nullptr, 0L, 0, 0L, HIDDEN,
      bh_g1, bl_g1, nullptr, bufB, nullptr, nullptr, sN256, HIDDEN, 0,
      gat1_al, gat1_ar, el, er, nullptr, nullptr, N_NODES);
  gat_agg_kernel<<<agrid, blk, 0, stream>>>(bufB, el, er, row_ptr, srcs, gat1_b, bufCh, bufCl);

  // ---- GIN layer 0: P = [h | feats] @ W1 (K=384), then aggregate P ----
  gemm_mfma<1, true, false><<<ggrid, blk, 0, stream>>>(nullptr,
      bufCh, bufCl, sN256, HIDDEN, HIDDEN, fhi, flo, 0L, F_IN, 0L, HIDDEN + F_IN,
      bh_i0w1, bl_i0w1, nullptr, bufB, nullptr, nullptr, sN256, HIDDEN, 0,
      nullptr, nullptr, nullptr, nullptr, nullptr, nullptr, N_NODES);
  gin_agg_kernel<<<agrid, blk, 0, stream>>>(bufB, row_ptr, srcs, gin0_eps, gin0_b1, bufA);
  hipMemsetAsync(bn_sums, 0, (size_t)NTYPE * 2 * HIDDEN * 4, stream);
  stats_kernel<<<dim3((N_NODES + 511) / 512, NTYPE), blk, 0, stream>>>(bufA, sN256, bn_sums);
  bn_finalize_kernel<<<1, NTYPE * HIDDEN, 0, stream>>>(bn_sums, gin0_g1, gin0_be1, bn_scale, bn_shift);
  gemm_mfma<2, false, true><<<ggrid, blk, 0, stream>>>(bufA,
      nullptr, nullptr, 0L, HIDDEN, HIDDEN, nullptr, nullptr, 0L, 0, sN256, HIDDEN,
      bh_i0w2, bl_i0w2, gin0_b2, nullptr, bufCh, bufCl, sN256, HIDDEN, 0,
      nullptr, nullptr, nullptr, nullptr, bn_scale, bn_shift, N_NODES);

  // ---- GIN layer 1 ----
  gemm_mfma<1, true, false><<<ggrid, blk, 0, stream>>>(nullptr,
      bufCh, bufCl, sN256, HIDDEN, HIDDEN, nullptr, nullptr, 0L, 0, 0L, HIDDEN,
      bh_i1w1, bl_i1w1, nullptr, bufB, nullptr, nullptr, sN256, HIDDEN, 0,
      nullptr, nullptr, nullptr, nullptr, nullptr, nullptr, N_NODES);
  gin_agg_kernel<<<agrid, blk, 0, stream>>>(bufB, row_ptr, srcs, gin1_eps, gin1_b1, bufA);
  hipMemsetAsync(bn_sums, 0, (size_t)NTYPE * 2 * HIDDEN * 4, stream);
  stats_kernel<<<dim3((N_NODES + 511) / 512, NTYPE), blk, 0, stream>>>(bufA, sN256, bn_sums);
  bn_finalize_kernel<<<1, NTYPE * HIDDEN, 0, stream>>>(bn_sums, gin1_g1, gin1_be1, bn_scale, bn_shift);
  gemm_mfma<2, false, false><<<ggrid, blk, 0, stream>>>(bufA,
      nullptr, nullptr, 0L, HIDDEN, HIDDEN, nullptr, nullptr, 0L, 0, sN256, HIDDEN,
      bh_i1w2, bl_i1w2, gin1_b2, out, nullptr, nullptr, 0L, NTYPE * HIDDEN, HIDDEN,
      nullptr, nullptr, nullptr, nullptr, bn_scale, bn_shift, N_NODES);
}

// Round 5
// 1553.002 us; speedup vs baseline: 1.4956x; 1.2062x over previous
//
#include <hip/hip_runtime.h>
#include <math.h>
#include <cstdint>

#define N_NODES 50000
#define F_IN    128
#define HIDDEN  256
#define NHEAD   4
#define HEADD   64
#define NEDGE   400000
#define NTYPE   2
#define SNB     256   // stats partial-reduction blocks per type

typedef unsigned short u16;
typedef float f32x4 __attribute__((ext_vector_type(4)));
typedef short s16x8 __attribute__((ext_vector_type(8)));

__device__ __forceinline__ float lrelu(float x) { return x > 0.f ? x : 0.2f * x; }

__device__ __forceinline__ void bsplit(float f, u16& hi, u16& lo) {
  unsigned u = __float_as_uint(f);
  hi = (u16)(u >> 16);
  float r = f - __uint_as_float(u & 0xffff0000u);
  lo = (u16)(__float_as_uint(r) >> 16);
}

__device__ __forceinline__ void gl_lds16(const void* g, void* l) {
  __builtin_amdgcn_global_load_lds(
      (const __attribute__((address_space(1))) void*)g,
      (__attribute__((address_space(3))) void*)l, 16, 0, 0);
}

// ============================ CSR build ============================
__global__ void hist_kernel(const int* __restrict__ dst0, const int* __restrict__ dst1,
                            int* __restrict__ counts) {
  int t = blockIdx.y;
  int e = blockIdx.x * blockDim.x + threadIdx.x;
  if (e >= NEDGE) return;
  const int* dst = t ? dst1 : dst0;
  atomicAdd(&counts[t * N_NODES + dst[e]], 1);
}

__launch_bounds__(1024)
__global__ void scan_kernel(const int* __restrict__ counts, int* __restrict__ row_ptr,
                            int* __restrict__ cursor) {
  int t = blockIdx.x;
  int tid = threadIdx.x;
  int lane = tid & 63, wv = tid >> 6;  // 16 waves
  __shared__ int wsum[16];
  int carry = 0;
  for (int base = 0; base < N_NODES; base += 1024) {
    int i = base + tid;
    int v = (i < N_NODES) ? counts[t * N_NODES + i] : 0;
    int x = v;
#pragma unroll
    for (int off = 1; off < 64; off <<= 1) {
      int u = __shfl_up(x, off);
      if (lane >= off) x += u;
    }
    if (lane == 63) wsum[wv] = x;
    __syncthreads();
    if (wv == 0 && lane < 16) {
      int y = wsum[lane];
#pragma unroll
      for (int off = 1; off < 16; off <<= 1) {
        int u = __shfl_up(y, off);
        if (lane >= off) y += u;
      }
      wsum[lane] = y;
    }
    __syncthreads();
    int blockoff = wv ? wsum[wv - 1] : 0;
    int tot = wsum[15];
    int excl = carry + blockoff + x - v;
    if (i < N_NODES) {
      row_ptr[t * (N_NODES + 1) + i] = excl;
      cursor[t * N_NODES + i] = excl;
    }
    carry += tot;
    __syncthreads();
  }
  if (tid == 0) row_ptr[t * (N_NODES + 1) + N_NODES] = carry;
}

__global__ void scatter_kernel(const int* __restrict__ src0, const int* __restrict__ dst0,
                               const int* __restrict__ src1, const int* __restrict__ dst1,
                               int* __restrict__ cursor, int* __restrict__ srcs) {
  int t = blockIdx.y;
  int e = blockIdx.x * blockDim.x + threadIdx.x;
  if (e >= NEDGE) return;
  const int* src = t ? src1 : src0;
  const int* dst = t ? dst1 : dst0;
  int d = dst[e];
  int pos = atomicAdd(&cursor[t * N_NODES + d], 1);
  srcs[t * NEDGE + pos] = src[e];
}

// ============================ prep: feats fp32 -> bf16 hi/lo ============================
__global__ void prep_feats_kernel(const float* __restrict__ f, u16* __restrict__ fh,
                                  u16* __restrict__ fl) {
  long i = ((long)blockIdx.x * blockDim.x + threadIdx.x) * 4;
  if (i >= (long)N_NODES * F_IN) return;
  float4 v = *(const float4*)(f + i);
  ushort4 hi, lo;
  bsplit(v.x, hi.x, lo.x);
  bsplit(v.y, hi.y, lo.y);
  bsplit(v.z, hi.z, lo.z);
  bsplit(v.w, hi.w, lo.w);
  *(ushort4*)(fh + i) = hi;
  *(ushort4*)(fl + i) = lo;
}

// ============================ weight prep: transpose + bf16 hi/lo split ============================
// W[t][K][256] fp32  ->  Bth/Btl[t][256][K] bf16
__launch_bounds__(256)
__global__ void prep_b_kernel(const float* __restrict__ W, u16* __restrict__ bth,
                              u16* __restrict__ btl, int K) {
  __shared__ unsigned tile[64][65];
  const int kt = blockIdx.x * 64, nt = blockIdx.y * 64, t = blockIdx.z;
  const int tid = threadIdx.x;
  const float* Wt = W + (size_t)t * K * 256;
  {
    int k = tid >> 2;
    int ncl = (tid & 3) * 16;
#pragma unroll
    for (int q = 0; q < 4; ++q) {
      float4 v = *(const float4*)(Wt + (size_t)(kt + k) * 256 + nt + ncl + q * 4);
      float f[4] = {v.x, v.y, v.z, v.w};
#pragma unroll
      for (int e = 0; e < 4; ++e) {
        u16 hi, lo;
        bsplit(f[e], hi, lo);
        tile[k][ncl + q * 4 + e] = (unsigned)hi | ((unsigned)lo << 16);
      }
    }
  }
  __syncthreads();
  {
    int n = tid & 63;
    int kc = (tid >> 6) * 16;
    u16 hi16[16], lo16[16];
#pragma unroll
    for (int i = 0; i < 16; ++i) {
      unsigned u = tile[kc + i][n];
      hi16[i] = (u16)(u & 0xffff);
      lo16[i] = (u16)(u >> 16);
    }
    size_t ob = ((size_t)t * 256 + nt + n) * K + kt + kc;
    *(s16x8*)(bth + ob)     = *(s16x8*)&hi16[0];
    *(s16x8*)(bth + ob + 8) = *(s16x8*)&hi16[8];
    *(s16x8*)(btl + ob)     = *(s16x8*)&lo16[0];
    *(s16x8*)(btl + ob + 8) = *(s16x8*)&lo16[8];
  }
}

// ============================ MFMA GEMM (bf16 3-term split) ============================
// MODE 0: GAT  — write z fp32; fused el/er (plain stores, single writer per slot)
// MODE 1: plain — write acc fp32 (P = A@W, no bias)
// MODE 2: A = fp32 with BN scale/shift + relu transform; out = relu(acc + bias)
// ASPLIT: A given as pre-split bf16 hi/lo (1 or 2 K-sources), staged via global_load_lds
// OSPLIT: epilogue writes bf16 hi/lo pair instead of fp32
// Tile BM=128,BN=128,BK=64; 4 waves (2x2), 64x64 per wave.
// LDS chunk-major: plane c (k-chunk of 8) stride 2048B, row stride 16B — conflict-free,
// and linear in lane order so global_load_lds (wave-uniform dest + lane*16) works.
template <int MODE, bool ASPLIT, bool OSPLIT>
__launch_bounds__(256)
__global__ void gemm_mfma(const float* __restrict__ Af,
                          const u16* __restrict__ A1h, const u16* __restrict__ A1l,
                          long strideA1, int ldA1, int KA1,
                          const u16* __restrict__ A2h, const u16* __restrict__ A2l,
                          long strideA2, int ldA2,
                          long strideAf, int K,
                          const u16* __restrict__ Bth, const u16* __restrict__ Btl,
                          const float* __restrict__ bias,
                          float* __restrict__ Cf, u16* __restrict__ Ch, u16* __restrict__ Cl,
                          long strideC, int ldC, int colOffT,
                          const float* __restrict__ al, const float* __restrict__ arv,
                          float* __restrict__ el, float* __restrict__ er,
                          const float* __restrict__ bnscale, const float* __restrict__ bnshift,
                          int M) {
  __shared__ __align__(16) char lds[65536];
  char* Ah = lds;
  char* Al = lds + 16384;
  char* Bh = lds + 32768;
  char* Bl = lds + 49152;

  const int t  = blockIdx.z;
  const int m0 = blockIdx.x * 128;
  const int n0 = blockIdx.y * 128;
  const int tid = threadIdx.x;
  const int lane = tid & 63;
  const int wid = tid >> 6;
  const int wm = wid >> 1, wn = wid & 1;
  const int lm = lane & 15, lg = lane >> 4;

  f32x4 acc[4][4];
#pragma unroll
  for (int i = 0; i < 4; ++i)
#pragma unroll
    for (int j = 0; j < 4; ++j) acc[i][j] = (f32x4)(0.f);

  // reg-staging assignment (MODE 2 only)
  const int ar2 = tid >> 1, akh = tid & 1;
  const bool avalid = (m0 + ar2) < M;
  const float* bsc = (MODE == 2) ? bnscale + (long)t * K : nullptr;
  const float* bsh = (MODE == 2) ? bnshift + (long)t * K : nullptr;

  for (int k0 = 0; k0 < K; k0 += 64) {
    if (k0) __syncthreads();
    if (ASPLIT) {
      // ---- A + B staging fully via global_load_lds (16 loads/wave) ----
#pragma unroll
      for (int q = 0; q < 8; ++q) {
        int v = wid * 8 + q;  // 0..31
        int c = (v >> 1) & 7, half = v & 1;
        bool hibuf = v < 16;
        // A
        int rowA = m0 + half * 64 + lane;
        if (rowA > M - 1) rowA = M - 1;
        const u16* ga;
        if (k0 < KA1)
          ga = (hibuf ? A1h : A1l) + (long)t * strideA1 + (long)rowA * ldA1 + k0 + c * 8;
        else
          ga = (hibuf ? A2h : A2l) + (long)t * strideA2 + (long)rowA * ldA2 + (k0 - KA1) + c * 8;
        gl_lds16(ga, (hibuf ? Ah : Al) + c * 2048 + half * 1024);
        // B
        int n = n0 + half * 64 + lane;
        const u16* gb = (hibuf ? Bth : Btl) + ((size_t)t * 256 + n) * K + k0 + c * 8;
        gl_lds16(gb, (hibuf ? Bh : Bl) + c * 2048 + half * 1024);
      }
    } else {
      // ---- B via global_load_lds (8 loads/wave) ----
#pragma unroll
      for (int q = 0; q < 8; ++q) {
        int v = wid * 8 + q;
        int c = (v >> 1) & 7, half = v & 1;
        bool hibuf = v < 16;
        int n = n0 + half * 64 + lane;
        const u16* gb = (hibuf ? Bth : Btl) + ((size_t)t * 256 + n) * K + k0 + c * 8;
        gl_lds16(gb, (hibuf ? Bh : Bl) + c * 2048 + half * 1024);
      }
      // ---- A: fp32 load + BN transform + split + ds_write ----
      float fv[32];
      const float* ap = Af + (long)t * strideAf + (long)(m0 + ar2) * ldA1 + k0 + akh * 32;
#pragma unroll
      for (int q = 0; q < 8; ++q) {
        float4 v = make_float4(0.f, 0.f, 0.f, 0.f);
        if (avalid) {
          v = *(const float4*)(ap + q * 4);
          if (MODE == 2) {
            int kb = k0 + akh * 32 + q * 4;
            float4 sc = *(const float4*)(bsc + kb);
            float4 sh = *(const float4*)(bsh + kb);
            v.x = fmaxf(fmaf(v.x, sc.x, sh.x), 0.f);
            v.y = fmaxf(fmaf(v.y, sc.y, sh.y), 0.f);
            v.z = fmaxf(fmaf(v.z, sc.z, sh.z), 0.f);
            v.w = fmaxf(fmaf(v.w, sc.w, sh.w), 0.f);
          }
        }
        fv[q * 4 + 0] = v.x; fv[q * 4 + 1] = v.y; fv[q * 4 + 2] = v.z; fv[q * 4 + 3] = v.w;
      }
#pragma unroll
      for (int cl_ = 0; cl_ < 4; ++cl_) {
        u16 hi[8], lo[8];
#pragma unroll
        for (int e = 0; e < 8; ++e) bsplit(fv[cl_ * 8 + e], hi[e], lo[e]);
        int off = (akh * 4 + cl_) * 2048 + ar2 * 16;
        *(s16x8*)(Ah + off) = *(s16x8*)&hi[0];
        *(s16x8*)(Al + off) = *(s16x8*)&lo[0];
      }
    }
    __syncthreads();
    // ---- MFMA ----
#pragma unroll
    for (int kk = 0; kk < 2; ++kk) {
      int c = kk * 4 + lg;
      s16x8 fAh[4], fAl[4], fBh[4], fBl[4];
#pragma unroll
      for (int i = 0; i < 4; ++i) {
        int off = c * 2048 + (wm * 64 + i * 16 + lm) * 16;
        fAh[i] = *(const s16x8*)(Ah + off);
        fAl[i] = *(const s16x8*)(Al + off);
      }
#pragma unroll
      for (int j = 0; j < 4; ++j) {
        int off = c * 2048 + (wn * 64 + j * 16 + lm) * 16;
        fBh[j] = *(const s16x8*)(Bh + off);
        fBl[j] = *(const s16x8*)(Bl + off);
      }
#pragma unroll
      for (int i = 0; i < 4; ++i)
#pragma unroll
        for (int j = 0; j < 4; ++j) {
          acc[i][j] = __builtin_amdgcn_mfma_f32_16x16x32_bf16(fAh[i], fBh[j], acc[i][j], 0, 0, 0);
          acc[i][j] = __builtin_amdgcn_mfma_f32_16x16x32_bf16(fAh[i], fBl[j], acc[i][j], 0, 0, 0);
          acc[i][j] = __builtin_amdgcn_mfma_f32_16x16x32_bf16(fAl[i], fBh[j], acc[i][j], 0, 0, 0);
        }
    }
  }

  // ---- epilogue ----
  if (MODE == 0) {
    const float* alt = al + t * HIDDEN;
    const float* art = arv + t * HIDDEN;
    const int head = (n0 + wn * 64) >> 6;
    float av[4], rv[4];
#pragma unroll
    for (int j = 0; j < 4; ++j) {
      int gc = n0 + wn * 64 + j * 16 + lm;
      av[j] = alt[gc];
      rv[j] = art[gc];
    }
#pragma unroll
    for (int i = 0; i < 4; ++i)
#pragma unroll
      for (int r = 0; r < 4; ++r) {
        float pel = 0.f, per = 0.f;
#pragma unroll
        for (int j = 0; j < 4; ++j) {
          pel = fmaf(acc[i][j][r], av[j], pel);
          per = fmaf(acc[i][j][r], rv[j], per);
        }
#pragma unroll
        for (int o = 1; o < 16; o <<= 1) {
          pel += __shfl_xor(pel, o);
          per += __shfl_xor(per, o);
        }
        int row = m0 + wm * 64 + i * 16 + lg * 4 + r;
        if (lm == 0 && row < M) {
          el[((long)t * N_NODES + row) * 4 + head] = pel;  // single writer
          er[((long)t * N_NODES + row) * 4 + head] = per;
        }
      }
  }

  float bv[4];
  if (MODE == 2) {
#pragma unroll
    for (int j = 0; j < 4; ++j) bv[j] = bias[t * HIDDEN + n0 + wn * 64 + j * 16 + lm];
  }
  const int colOff = colOffT * t;
#pragma unroll
  for (int i = 0; i < 4; ++i)
#pragma unroll
    for (int r = 0; r < 4; ++r) {
      int row = m0 + wm * 64 + i * 16 + lg * 4 + r;
      if (row < M) {
#pragma unroll
        for (int j = 0; j < 4; ++j) {
          int col = n0 + wn * 64 + j * 16 + lm;
          float v = acc[i][j][r];
          if (MODE == 2) v = fmaxf(v + bv[j], 0.f);
          if (OSPLIT) {
            u16 hi, lo;
            bsplit(v, hi, lo);
            Ch[(long)t * strideC + (long)row * ldC + col] = hi;
            Cl[(long)t * strideC + (long)row * ldC + col] = lo;
          } else {
            Cf[(long)t * strideC + colOff + (long)row * ldC + col] = v;
          }
        }
      }
    }
}

// ============================ GAT aggregation (out: bf16 hi/lo) ============================
__launch_bounds__(256)
__global__ void gat_agg_kernel(const float* __restrict__ z, const float* __restrict__ el,
                               const float* __restrict__ er, const int* __restrict__ row_ptr,
                               const int* __restrict__ srcs, const float* __restrict__ bias,
                               u16* __restrict__ Hh, u16* __restrict__ Hl) {
  int t = blockIdx.y;
  int wv = threadIdx.x >> 6, lane = threadIdx.x & 63;
  int dst = blockIdx.x * 4 + wv;
  if (dst >= N_NODES) return;
  const int* rp = row_ptr + t * (N_NODES + 1);
  int beg = rp[dst], end = rp[dst + 1];
  const float* elt = el + (long)t * N_NODES * 4;
  const float* zt  = z + (long)t * N_NODES * HIDDEN;
  const int* st = srcs + (long)t * NEDGE;
  float4 erd = *(const float4*)(er + (long)t * N_NODES * 4 + (long)dst * 4);

  float m0 = -INFINITY, m1 = -INFINITY, m2 = -INFINITY, m3 = -INFINITY;
  for (int j = beg + lane; j < end; j += 64) {
    int s = st[j];
    float4 ev = *(const float4*)(elt + (long)s * 4);
    m0 = fmaxf(m0, lrelu(ev.x + erd.x));
    m1 = fmaxf(m1, lrelu(ev.y + erd.y));
    m2 = fmaxf(m2, lrelu(ev.z + erd.z));
    m3 = fmaxf(m3, lrelu(ev.w + erd.w));
  }
#pragma unroll
  for (int off = 32; off; off >>= 1) {
    m0 = fmaxf(m0, __shfl_xor(m0, off));
    m1 = fmaxf(m1, __shfl_xor(m1, off));
    m2 = fmaxf(m2, __shfl_xor(m2, off));
    m3 = fmaxf(m3, __shfl_xor(m3, off));
  }
  float d0 = 0, d1 = 0, d2 = 0, d3 = 0;
  for (int j = beg + lane; j < end; j += 64) {
    int s = st[j];
    float4 ev = *(const float4*)(elt + (long)s * 4);
    d0 += __expf(lrelu(ev.x + erd.x) - m0);
    d1 += __expf(lrelu(ev.y + erd.y) - m1);
    d2 += __expf(lrelu(ev.z + erd.z) - m2);
    d3 += __expf(lrelu(ev.w + erd.w) - m3);
  }
#pragma unroll
  for (int off = 32; off; off >>= 1) {
    d0 += __shfl_xor(d0, off);
    d1 += __shfl_xor(d1, off);
    d2 += __shfl_xor(d2, off);
    d3 += __shfl_xor(d3, off);
  }
  int hl = lane >> 4;
  float mh  = (hl == 0) ? m0 : (hl == 1) ? m1 : (hl == 2) ? m2 : m3;
  float dh  = (hl == 0) ? d0 : (hl == 1) ? d1 : (hl == 2) ? d2 : d3;
  float erh = (hl == 0) ? erd.x : (hl == 1) ? erd.y : (hl == 2) ? erd.z : erd.w;
  float inv = 1.0f / fmaxf(dh, 1e-9f);
  float a0 = 0, a1 = 0, a2 = 0, a3 = 0;
  for (int j = beg; j < end; ++j) {
    int s = st[j];
    float eh = lrelu(elt[(long)s * 4 + hl] + erh);
    float w = __expf(eh - mh) * inv;
    float4 zv = *(const float4*)(zt + (long)s * HIDDEN + lane * 4);
    a0 = fmaf(w, zv.x, a0);
    a1 = fmaf(w, zv.y, a1);
    a2 = fmaf(w, zv.z, a2);
    a3 = fmaf(w, zv.w, a3);
  }
  float4 bv = *(const float4*)(bias + t * HIDDEN + lane * 4);
  float o0 = fmaxf(a0 + bv.x, 0.f);
  float o1 = fmaxf(a1 + bv.y, 0.f);
  float o2 = fmaxf(a2 + bv.z, 0.f);
  float o3 = fmaxf(a3 + bv.w, 0.f);
  ushort4 hi, lo;
  bsplit(o0, hi.x, lo.x);
  bsplit(o1, hi.y, lo.y);
  bsplit(o2, hi.z, lo.z);
  bsplit(o3, hi.w, lo.w);
  long ob = (long)t * N_NODES * HIDDEN + (long)dst * HIDDEN + lane * 4;
  *(ushort4*)(Hh + ob) = hi;
  *(ushort4*)(Hl + ob) = lo;
}

// ============================ GIN aggregation on P ============================
// y = (1+eps)*P[dst] + sum_{src} P[src] + b1
__launch_bounds__(256)
__global__ void gin_agg_kernel(const float* __restrict__ P, const int* __restrict__ row_ptr,
                               const int* __restrict__ srcs, const float* __restrict__ epsArr,
                               const float* __restrict__ b1, float* __restrict__ y) {
  int t = blockIdx.y;
  int wv = threadIdx.x >> 6, lane = threadIdx.x & 63;
  int dst = blockIdx.x * 4 + wv;
  if (dst >= N_NODES) return;
  const int* rp = row_ptr + t * (N_NODES + 1);
  int beg = rp[dst], end = rp[dst + 1];
  const float* Pt = P + (long)t * N_NODES * HIDDEN;
  const int* st = srcs + (long)t * NEDGE;
  float ep = 1.0f + epsArr[t];
  float a0 = 0, a1 = 0, a2 = 0, a3 = 0;
  for (int j = beg; j < end; ++j) {
    int s = st[j];
    float4 pv = *(const float4*)(Pt + (long)s * HIDDEN + lane * 4);
    a0 += pv.x; a1 += pv.y; a2 += pv.z; a3 += pv.w;
  }
  float4 ps = *(const float4*)(Pt + (long)dst * HIDDEN + lane * 4);
  float4 bb = *(const float4*)(b1 + t * HIDDEN + lane * 4);
  float4 o;
  o.x = fmaf(ep, ps.x, a0) + bb.x;
  o.y = fmaf(ep, ps.y, a1) + bb.y;
  o.z = fmaf(ep, ps.z, a2) + bb.z;
  o.w = fmaf(ep, ps.w, a3) + bb.w;
  *(float4*)(y + (long)t * N_NODES * HIDDEN + (long)dst * HIDDEN + lane * 4) = o;
}

// ============================ BN stats (two-level, no atomics) ============================
// Each block: contiguous row chunk, 4 rows in flight (256 thr = 4 x 64-lane row-groups),
// float4 per lane -> fully coalesced 1KB/row. LDS-reduce 4 groups -> per-block partials.
__launch_bounds__(256)
__global__ void stats_kernel(const float* __restrict__ y, long strideY,
                             float* __restrict__ partials) {  // [T][SNB][512]
  const int t = blockIdx.y, blk = blockIdx.x;
  const int tid = threadIdx.x;
  const int col4 = (tid & 63) * 4;
  const int rsub = tid >> 6;
  const int chunk = (N_NODES + SNB - 1) / SNB;
  const int r0 = blk * chunk;
  const int rend = min(r0 + chunk, N_NODES);
  const float* yt = y + (long)t * strideY;
  float s[4] = {0.f, 0.f, 0.f, 0.f}, s2[4] = {0.f, 0.f, 0.f, 0.f};
  for (int r = r0 + rsub; r < rend; r += 4) {
    float4 v = *(const float4*)(yt + (long)r * HIDDEN + col4);
    s[0] += v.x; s2[0] = fmaf(v.x, v.x, s2[0]);
    s[1] += v.y; s2[1] = fmaf(v.y, v.y, s2[1]);
    s[2] += v.z; s2[2] = fmaf(v.z, v.z, s2[2]);
    s[3] += v.w; s2[3] = fmaf(v.w, v.w, s2[3]);
  }
  __shared__ float ls[4][512];
#pragma unroll
  for (int e = 0; e < 4; ++e) {
    ls[rsub][col4 + e] = s[e];
    ls[rsub][256 + col4 + e] = s2[e];
  }
  __syncthreads();
  for (int i = tid; i < 512; i += 256) {
    float v = ls[0][i] + ls[1][i] + ls[2][i] + ls[3][i];
    partials[((long)t * SNB + blk) * 512 + i] = v;
  }
}

__global__ void bn_finalize_kernel(const float* __restrict__ partials,
                                   const float* __restrict__ g1, const float* __restrict__ be1,
                                   float* __restrict__ scale, float* __restrict__ shift) {
  int i = threadIdx.x + blockIdx.x * blockDim.x;
  if (i >= NTYPE * HIDDEN) return;
  int t = i / HIDDEN, c = i % HIDDEN;
  float s = 0.f, s2 = 0.f;
  for (int b = 0; b < SNB; ++b) {
    s  += partials[((long)t * SNB + b) * 512 + c];
    s2 += partials[((long)t * SNB + b) * 512 + 256 + c];
  }
  float mu  = s * (1.0f / N_NODES);
  float ms  = s2 * (1.0f / N_NODES);
  float var = ms - mu * mu;
  float sc = g1[i] * rsqrtf(var + 1e-5f);
  scale[i] = sc;
  shift[i] = be1[i] - mu * sc;
}

// ============================ launch ============================
extern "C" void kernel_launch(void* const* d_in, const int* in_sizes, int n_in,
                              void* d_out, int out_size, void* d_ws, size_t ws_size,
                              hipStream_t stream) {
  const float* feats   = (const float*)d_in[0];
  const int* src0      = (const int*)d_in[1];
  const int* dst0      = (const int*)d_in[2];
  const int* src1      = (const int*)d_in[3];
  const int* dst1      = (const int*)d_in[4];
  const float* gat0_W  = (const float*)d_in[5];
  const float* gat0_al = (const float*)d_in[6];
  const float* gat0_ar = (const float*)d_in[7];
  const float* gat0_b  = (const float*)d_in[8];
  const float* gat1_W  = (const float*)d_in[9];
  const float* gat1_al = (const float*)d_in[10];
  const float* gat1_ar = (const float*)d_in[11];
  const float* gat1_b  = (const float*)d_in[12];
  const float* gin0_eps = (const float*)d_in[13];
  const float* gin0_W1  = (const float*)d_in[14];
  const float* gin0_b1  = (const float*)d_in[15];
  const float* gin0_g1  = (const float*)d_in[16];
  const float* gin0_be1 = (const float*)d_in[17];
  const float* gin0_W2  = (const float*)d_in[18];
  const float* gin0_b2  = (const float*)d_in[19];
  const float* gin1_eps = (const float*)d_in[20];
  const float* gin1_W1  = (const float*)d_in[21];
  const float* gin1_b1  = (const float*)d_in[22];
  const float* gin1_g1  = (const float*)d_in[23];
  const float* gin1_be1 = (const float*)d_in[24];
  const float* gin1_W2  = (const float*)d_in[25];
  const float* gin1_b2  = (const float*)d_in[26];
  float* out = (float*)d_out;

  char* p = (char*)d_ws;
  size_t off = 0;
  auto take = [&](size_t bytes) -> void* {
    void* r = p + off;
    off = (off + bytes + 255) & ~(size_t)255;
    return r;
  };
  float* bufA  = (float*)take((size_t)NTYPE * N_NODES * HIDDEN * 4);  // y
  float* bufB  = (float*)take((size_t)NTYPE * N_NODES * HIDDEN * 4);  // z / P
  u16*   bufCh = (u16*)take((size_t)NTYPE * N_NODES * HIDDEN * 2);    // h hi
  u16*   bufCl = (u16*)take((size_t)NTYPE * N_NODES * HIDDEN * 2);    // h lo
  u16*   fhi   = (u16*)take((size_t)N_NODES * F_IN * 2);
  u16*   flo   = (u16*)take((size_t)N_NODES * F_IN * 2);
  float* el   = (float*)take((size_t)NTYPE * N_NODES * 4 * 4);
  float* er   = (float*)take((size_t)NTYPE * N_NODES * 4 * 4);
  int* counts  = (int*)take((size_t)NTYPE * N_NODES * 4);
  int* row_ptr = (int*)take((size_t)NTYPE * (N_NODES + 1) * 4);
  int* cursor  = (int*)take((size_t)NTYPE * N_NODES * 4);
  int* srcs    = (int*)take((size_t)NTYPE * NEDGE * 4);
  float* bn_part  = (float*)take((size_t)NTYPE * SNB * 512 * 4);
  float* bn_scale = (float*)take((size_t)NTYPE * HIDDEN * 4);
  float* bn_shift = (float*)take((size_t)NTYPE * HIDDEN * 4);
  u16* bh_g0   = (u16*)take((size_t)NTYPE * 256 * 128 * 2);
  u16* bl_g0   = (u16*)take((size_t)NTYPE * 256 * 128 * 2);
  u16* bh_g1   = (u16*)take((size_t)NTYPE * 256 * 256 * 2);
  u16* bl_g1   = (u16*)take((size_t)NTYPE * 256 * 256 * 2);
  u16* bh_i0w1 = (u16*)take((size_t)NTYPE * 256 * 384 * 2);
  u16* bl_i0w1 = (u16*)take((size_t)NTYPE * 256 * 384 * 2);
  u16* bh_i0w2 = (u16*)take((size_t)NTYPE * 256 * 256 * 2);
  u16* bl_i0w2 = (u16*)take((size_t)NTYPE * 256 * 256 * 2);
  u16* bh_i1w1 = (u16*)take((size_t)NTYPE * 256 * 256 * 2);
  u16* bl_i1w1 = (u16*)take((size_t)NTYPE * 256 * 256 * 2);
  u16* bh_i1w2 = (u16*)take((size_t)NTYPE * 256 * 256 * 2);
  u16* bl_i1w2 = (u16*)take((size_t)NTYPE * 256 * 256 * 2);
  (void)ws_size; (void)in_sizes; (void)n_in; (void)out_size;

  const dim3 blk(256);
  const int egrid = (NEDGE + 255) / 256;
  const dim3 ggrid((N_NODES + 127) / 128, 2, NTYPE);
  const dim3 agrid((N_NODES + 3) / 4, NTYPE);
  const dim3 sgrid(SNB, NTYPE);
  const long sN256 = (long)N_NODES * HIDDEN;

  // ---- prep ----
  prep_feats_kernel<<<(N_NODES * F_IN / 4 + 255) / 256, blk, 0, stream>>>(feats, fhi, flo);
  prep_b_kernel<<<dim3(2, 4, NTYPE), blk, 0, stream>>>(gat0_W, bh_g0, bl_g0, 128);
  prep_b_kernel<<<dim3(4, 4, NTYPE), blk, 0, stream>>>(gat1_W, bh_g1, bl_g1, 256);
  prep_b_kernel<<<dim3(6, 4, NTYPE), blk, 0, stream>>>(gin0_W1, bh_i0w1, bl_i0w1, 384);
  prep_b_kernel<<<dim3(4, 4, NTYPE), blk, 0, stream>>>(gin0_W2, bh_i0w2, bl_i0w2, 256);
  prep_b_kernel<<<dim3(4, 4, NTYPE), blk, 0, stream>>>(gin1_W1, bh_i1w1, bl_i1w1, 256);
  prep_b_kernel<<<dim3(4, 4, NTYPE), blk, 0, stream>>>(gin1_W2, bh_i1w2, bl_i1w2, 256);

  // ---- CSR build ----
  hipMemsetAsync(counts, 0, (size_t)NTYPE * N_NODES * 4, stream);
  hist_kernel<<<dim3(egrid, NTYPE), blk, 0, stream>>>(dst0, dst1, counts);
  scan_kernel<<<NTYPE, 1024, 0, stream>>>(counts, row_ptr, cursor);
  scatter_kernel<<<dim3(egrid, NTYPE), blk, 0, stream>>>(src0, dst0, src1, dst1, cursor, srcs);

  // ---- GAT layer 0 ----
  gemm_mfma<0, true, false><<<ggrid, blk, 0, stream>>>(nullptr,
      fhi, flo, 0L, F_IN, F_IN, nullptr, nullptr, 0L, 0, 0L, F_IN,
      bh_g0, bl_g0, nullptr, bufB, nullptr, nullptr, sN256, HIDDEN, 0,
      gat0_al, gat0_ar, el, er, nullptr, nullptr, N_NODES);
  gat_agg_kernel<<<agrid, blk, 0, stream>>>(bufB, el, er, row_ptr, srcs, gat0_b, bufCh, bufCl);

  // ---- GAT layer 1 ----
  gemm_mfma<0, true, false><<<ggrid, blk, 0, stream>>>(nullptr,
      bufCh, bufCl, sN256, HIDDEN, HIDDEN, nullptr, nullptr, 0L, 0, 0L, HIDDEN,
      bh_g1, bl_g1, nullptr, bufB, nullptr, nullptr, sN256, HIDDEN, 0,
      gat1_al, gat1_ar, el, er, nullptr, nullptr, N_NODES);
  gat_agg_kernel<<<agrid, blk, 0, stream>>>(bufB, el, er, row_ptr, srcs, gat1_b, bufCh, bufCl);

  // ---- GIN layer 0: P = [h | feats] @ W1 (K=384), then aggregate P ----
  gemm_mfma<1, true, false><<<ggrid, blk, 0, stream>>>(nullptr,
      bufCh, bufCl, sN256, HIDDEN, HIDDEN, fhi, flo, 0L, F_IN, 0L, HIDDEN + F_IN,
      bh_i0w1, bl_i0w1, nullptr, bufB, nullptr, nullptr, sN256, HIDDEN, 0,
      nullptr, nullptr, nullptr, nullptr, nullptr, nullptr, N_NODES);
  gin_agg_kernel<<<agrid, blk, 0, stream>>>(bufB, row_ptr, srcs, gin0_eps, gin0_b1, bufA);
  stats_kernel<<<sgrid, blk, 0, stream>>>(bufA, sN256, bn_part);
  bn_finalize_kernel<<<1, NTYPE * HIDDEN, 0, stream>>>(bn_part, gin0_g1, gin0_be1, bn_scale, bn_shift);
  gemm_mfma<2, false, true><<<ggrid, blk, 0, stream>>>(bufA,
      nullptr, nullptr, 0L, HIDDEN, HIDDEN, nullptr, nullptr, 0L, 0, sN256, HIDDEN,
      bh_i0w2, bl_i0w2, gin0_b2, nullptr, bufCh, bufCl, sN256, HIDDEN, 0,
      nullptr, nullptr, nullptr, nullptr, bn_scale, bn_shift, N_NODES);

  // ---- GIN layer 1 ----
  gemm_mfma<1, true, false><<<ggrid, blk, 0, stream>>>(nullptr,
      bufCh, bufCl, sN256, HIDDEN, HIDDEN, nullptr, nullptr, 0L, 0, 0L, HIDDEN,
      bh_i1w1, bl_i1w1, nullptr, bufB, nullptr, nullptr, sN256, HIDDEN, 0,
      nullptr, nullptr, nullptr, nullptr, nullptr, nullptr, N_NODES);
  gin_agg_kernel<<<agrid, blk, 0, stream>>>(bufB, row_ptr, srcs, gin1_eps, gin1_b1, bufA);
  stats_kernel<<<sgrid, blk, 0, stream>>>(bufA, sN256, bn_part);
  bn_finalize_kernel<<<1, NTYPE * HIDDEN, 0, stream>>>(bn_part, gin1_g1, gin1_be1, bn_scale, bn_shift);
  gemm_mfma<2, false, false><<<ggrid, blk, 0, stream>>>(bufA,
      nullptr, nullptr, 0L, HIDDEN, HIDDEN, nullptr, nullptr, 0L, 0, sN256, HIDDEN,
      bh_i1w2, bl_i1w2, gin1_b2, out, nullptr, nullptr, 0L, NTYPE * HIDDEN, HIDDEN,
      nullptr, nullptr, nullptr, nullptr, bn_scale, bn_shift, N_NODES);
}

// Round 6
// 1445.994 us; speedup vs baseline: 1.6062x; 1.0740x over previous
//
#include <hip/hip_runtime.h>
#include <hip/hip_fp16.h>
#include <math.h>
#include <cstdint>

#define N_NODES 50000
#define F_IN    128
#define HIDDEN  256
#define NHEAD   4
#define HEADD   64
#define NEDGE   400000
#define NTYPE   2
#define SNB     256   // stats partial-reduction blocks per type

typedef unsigned short u16;
typedef float f32x4 __attribute__((ext_vector_type(4)));
typedef short s16x8 __attribute__((ext_vector_type(8)));

__device__ __forceinline__ float lrelu(float x) { return x > 0.f ? x : 0.2f * x; }

__device__ __forceinline__ void bsplit(float f, u16& hi, u16& lo) {
  unsigned u = __float_as_uint(f);
  hi = (u16)(u >> 16);
  float r = f - __uint_as_float(u & 0xffff0000u);
  lo = (u16)(__float_as_uint(r) >> 16);
}

__device__ __forceinline__ u16 f2h(float f) {
  return __half_as_ushort(__float2half(f));
}

__device__ __forceinline__ void gl_lds16(const void* g, void* l) {
  __builtin_amdgcn_global_load_lds(
      (const __attribute__((address_space(1))) void*)g,
      (__attribute__((address_space(3))) void*)l, 16, 0, 0);
}

// ============================ CSR build ============================
__global__ void hist_kernel(const int* __restrict__ dst0, const int* __restrict__ dst1,
                            int* __restrict__ counts) {
  int t = blockIdx.y;
  int e = blockIdx.x * blockDim.x + threadIdx.x;
  if (e >= NEDGE) return;
  const int* dst = t ? dst1 : dst0;
  atomicAdd(&counts[t * N_NODES + dst[e]], 1);
}

__launch_bounds__(1024)
__global__ void scan_kernel(const int* __restrict__ counts, int* __restrict__ row_ptr,
                            int* __restrict__ cursor) {
  int t = blockIdx.x;
  int tid = threadIdx.x;
  int lane = tid & 63, wv = tid >> 6;  // 16 waves
  __shared__ int wsum[16];
  int carry = 0;
  for (int base = 0; base < N_NODES; base += 1024) {
    int i = base + tid;
    int v = (i < N_NODES) ? counts[t * N_NODES + i] : 0;
    int x = v;
#pragma unroll
    for (int off = 1; off < 64; off <<= 1) {
      int u = __shfl_up(x, off);
      if (lane >= off) x += u;
    }
    if (lane == 63) wsum[wv] = x;
    __syncthreads();
    if (wv == 0 && lane < 16) {
      int y = wsum[lane];
#pragma unroll
      for (int off = 1; off < 16; off <<= 1) {
        int u = __shfl_up(y, off);
        if (lane >= off) y += u;
      }
      wsum[lane] = y;
    }
    __syncthreads();
    int blockoff = wv ? wsum[wv - 1] : 0;
    int tot = wsum[15];
    int excl = carry + blockoff + x - v;
    if (i < N_NODES) {
      row_ptr[t * (N_NODES + 1) + i] = excl;
      cursor[t * N_NODES + i] = excl;
    }
    carry += tot;
    __syncthreads();
  }
  if (tid == 0) row_ptr[t * (N_NODES + 1) + N_NODES] = carry;
}

__global__ void scatter_kernel(const int* __restrict__ src0, const int* __restrict__ dst0,
                               const int* __restrict__ src1, const int* __restrict__ dst1,
                               int* __restrict__ cursor, int* __restrict__ srcs) {
  int t = blockIdx.y;
  int e = blockIdx.x * blockDim.x + threadIdx.x;
  if (e >= NEDGE) return;
  const int* src = t ? src1 : src0;
  const int* dst = t ? dst1 : dst0;
  int d = dst[e];
  int pos = atomicAdd(&cursor[t * N_NODES + d], 1);
  srcs[t * NEDGE + pos] = src[e];
}

// ============================ prep: feats fp32 -> bf16 hi/lo ============================
__global__ void prep_feats_kernel(const float* __restrict__ f, u16* __restrict__ fh,
                                  u16* __restrict__ fl) {
  long i = ((long)blockIdx.x * blockDim.x + threadIdx.x) * 4;
  if (i >= (long)N_NODES * F_IN) return;
  float4 v = *(const float4*)(f + i);
  ushort4 hi, lo;
  bsplit(v.x, hi.x, lo.x);
  bsplit(v.y, hi.y, lo.y);
  bsplit(v.z, hi.z, lo.z);
  bsplit(v.w, hi.w, lo.w);
  *(ushort4*)(fh + i) = hi;
  *(ushort4*)(fl + i) = lo;
}

// ============================ weight prep: transpose + bf16 hi/lo split ============================
// W[t][K][256] fp32  ->  Bth/Btl[t][256][K] bf16
__launch_bounds__(256)
__global__ void prep_b_kernel(const float* __restrict__ W, u16* __restrict__ bth,
                              u16* __restrict__ btl, int K) {
  __shared__ unsigned tile[64][65];
  const int kt = blockIdx.x * 64, nt = blockIdx.y * 64, t = blockIdx.z;
  const int tid = threadIdx.x;
  const float* Wt = W + (size_t)t * K * 256;
  {
    int k = tid >> 2;
    int ncl = (tid & 3) * 16;
#pragma unroll
    for (int q = 0; q < 4; ++q) {
      float4 v = *(const float4*)(Wt + (size_t)(kt + k) * 256 + nt + ncl + q * 4);
      float f[4] = {v.x, v.y, v.z, v.w};
#pragma unroll
      for (int e = 0; e < 4; ++e) {
        u16 hi, lo;
        bsplit(f[e], hi, lo);
        tile[k][ncl + q * 4 + e] = (unsigned)hi | ((unsigned)lo << 16);
      }
    }
  }
  __syncthreads();
  {
    int n = tid & 63;
    int kc = (tid >> 6) * 16;
    u16 hi16[16], lo16[16];
#pragma unroll
    for (int i = 0; i < 16; ++i) {
      unsigned u = tile[kc + i][n];
      hi16[i] = (u16)(u & 0xffff);
      lo16[i] = (u16)(u >> 16);
    }
    size_t ob = ((size_t)t * 256 + nt + n) * K + kt + kc;
    *(s16x8*)(bth + ob)     = *(s16x8*)&hi16[0];
    *(s16x8*)(bth + ob + 8) = *(s16x8*)&hi16[8];
    *(s16x8*)(btl + ob)     = *(s16x8*)&lo16[0];
    *(s16x8*)(btl + ob + 8) = *(s16x8*)&lo16[8];
  }
}

// ============================ MFMA GEMM (bf16 3-term split) ============================
// MODE 0: GAT  — fused el/er (plain stores, single writer per slot)
// MODE 1: plain P = A@W (no bias)
// MODE 2: A = fp32 with BN scale/shift + relu transform; out = relu(acc + bias)
// ASPLIT: A given as pre-split bf16 hi/lo (1 or 2 K-sources), staged via global_load_lds
// OUTK: 0 = fp32 (Cf, +colOff), 1 = bf16 hi/lo split (Ch/Cl), 2 = fp16 (Ch)
// Tile BM=128,BN=128,BK=64; 4 waves (2x2), 64x64 per wave.
// LDS chunk-major: plane c (k-chunk of 8) stride 2048B, row stride 16B — conflict-free,
// and linear in lane order so global_load_lds (wave-uniform dest + lane*16) works.
template <int MODE, bool ASPLIT, int OUTK>
__launch_bounds__(256)
__global__ void gemm_mfma(const float* __restrict__ Af,
                          const u16* __restrict__ A1h, const u16* __restrict__ A1l,
                          long strideA1, int ldA1, int KA1,
                          const u16* __restrict__ A2h, const u16* __restrict__ A2l,
                          long strideA2, int ldA2,
                          long strideAf, int K,
                          const u16* __restrict__ Bth, const u16* __restrict__ Btl,
                          const float* __restrict__ bias,
                          float* __restrict__ Cf, u16* __restrict__ Ch, u16* __restrict__ Cl,
                          long strideC, int ldC, int colOffT,
                          const float* __restrict__ al, const float* __restrict__ arv,
                          float* __restrict__ el, float* __restrict__ er,
                          const float* __restrict__ bnscale, const float* __restrict__ bnshift,
                          int M) {
  __shared__ __align__(16) char lds[65536];
  char* Ah = lds;
  char* Al = lds + 16384;
  char* Bh = lds + 32768;
  char* Bl = lds + 49152;

  const int t  = blockIdx.z;
  const int m0 = blockIdx.x * 128;
  const int n0 = blockIdx.y * 128;
  const int tid = threadIdx.x;
  const int lane = tid & 63;
  const int wid = tid >> 6;
  const int wm = wid >> 1, wn = wid & 1;
  const int lm = lane & 15, lg = lane >> 4;

  f32x4 acc[4][4];
#pragma unroll
  for (int i = 0; i < 4; ++i)
#pragma unroll
    for (int j = 0; j < 4; ++j) acc[i][j] = (f32x4)(0.f);

  // reg-staging assignment (MODE 2 only)
  const int ar2 = tid >> 1, akh = tid & 1;
  const bool avalid = (m0 + ar2) < M;
  const float* bsc = (MODE == 2) ? bnscale + (long)t * K : nullptr;
  const float* bsh = (MODE == 2) ? bnshift + (long)t * K : nullptr;

  for (int k0 = 0; k0 < K; k0 += 64) {
    if (k0) __syncthreads();
    if (ASPLIT) {
      // ---- A + B staging fully via global_load_lds (16 loads/wave) ----
#pragma unroll
      for (int q = 0; q < 8; ++q) {
        int v = wid * 8 + q;  // 0..31
        int c = (v >> 1) & 7, half = v & 1;
        bool hibuf = v < 16;
        // A
        int rowA = m0 + half * 64 + lane;
        if (rowA > M - 1) rowA = M - 1;
        const u16* ga;
        if (k0 < KA1)
          ga = (hibuf ? A1h : A1l) + (long)t * strideA1 + (long)rowA * ldA1 + k0 + c * 8;
        else
          ga = (hibuf ? A2h : A2l) + (long)t * strideA2 + (long)rowA * ldA2 + (k0 - KA1) + c * 8;
        gl_lds16(ga, (hibuf ? Ah : Al) + c * 2048 + half * 1024);
        // B
        int n = n0 + half * 64 + lane;
        const u16* gb = (hibuf ? Bth : Btl) + ((size_t)t * 256 + n) * K + k0 + c * 8;
        gl_lds16(gb, (hibuf ? Bh : Bl) + c * 2048 + half * 1024);
      }
    } else {
      // ---- B via global_load_lds (8 loads/wave) ----
#pragma unroll
      for (int q = 0; q < 8; ++q) {
        int v = wid * 8 + q;
        int c = (v >> 1) & 7, half = v & 1;
        bool hibuf = v < 16;
        int n = n0 + half * 64 + lane;
        const u16* gb = (hibuf ? Bth : Btl) + ((size_t)t * 256 + n) * K + k0 + c * 8;
        gl_lds16(gb, (hibuf ? Bh : Bl) + c * 2048 + half * 1024);
      }
      // ---- A: fp32 load + BN transform + split + ds_write ----
      float fv[32];
      const float* ap = Af + (long)t * strideAf + (long)(m0 + ar2) * ldA1 + k0 + akh * 32;
#pragma unroll
      for (int q = 0; q < 8; ++q) {
        float4 v = make_float4(0.f, 0.f, 0.f, 0.f);
        if (avalid) {
          v = *(const float4*)(ap + q * 4);
          if (MODE == 2) {
            int kb = k0 + akh * 32 + q * 4;
            float4 sc = *(const float4*)(bsc + kb);
            float4 sh = *(const float4*)(bsh + kb);
            v.x = fmaxf(fmaf(v.x, sc.x, sh.x), 0.f);
            v.y = fmaxf(fmaf(v.y, sc.y, sh.y), 0.f);
            v.z = fmaxf(fmaf(v.z, sc.z, sh.z), 0.f);
            v.w = fmaxf(fmaf(v.w, sc.w, sh.w), 0.f);
          }
        }
        fv[q * 4 + 0] = v.x; fv[q * 4 + 1] = v.y; fv[q * 4 + 2] = v.z; fv[q * 4 + 3] = v.w;
      }
#pragma unroll
      for (int cl_ = 0; cl_ < 4; ++cl_) {
        u16 hi[8], lo[8];
#pragma unroll
        for (int e = 0; e < 8; ++e) bsplit(fv[cl_ * 8 + e], hi[e], lo[e]);
        int off = (akh * 4 + cl_) * 2048 + ar2 * 16;
        *(s16x8*)(Ah + off) = *(s16x8*)&hi[0];
        *(s16x8*)(Al + off) = *(s16x8*)&lo[0];
      }
    }
    __syncthreads();
    // ---- MFMA ----
#pragma unroll
    for (int kk = 0; kk < 2; ++kk) {
      int c = kk * 4 + lg;
      s16x8 fAh[4], fAl[4], fBh[4], fBl[4];
#pragma unroll
      for (int i = 0; i < 4; ++i) {
        int off = c * 2048 + (wm * 64 + i * 16 + lm) * 16;
        fAh[i] = *(const s16x8*)(Ah + off);
        fAl[i] = *(const s16x8*)(Al + off);
      }
#pragma unroll
      for (int j = 0; j < 4; ++j) {
        int off = c * 2048 + (wn * 64 + j * 16 + lm) * 16;
        fBh[j] = *(const s16x8*)(Bh + off);
        fBl[j] = *(const s16x8*)(Bl + off);
      }
#pragma unroll
      for (int i = 0; i < 4; ++i)
#pragma unroll
        for (int j = 0; j < 4; ++j) {
          acc[i][j] = __builtin_amdgcn_mfma_f32_16x16x32_bf16(fAh[i], fBh[j], acc[i][j], 0, 0, 0);
          acc[i][j] = __builtin_amdgcn_mfma_f32_16x16x32_bf16(fAh[i], fBl[j], acc[i][j], 0, 0, 0);
          acc[i][j] = __builtin_amdgcn_mfma_f32_16x16x32_bf16(fAl[i], fBh[j], acc[i][j], 0, 0, 0);
        }
    }
  }

  // ---- epilogue ----
  if (MODE == 0) {
    const float* alt = al + t * HIDDEN;
    const float* art = arv + t * HIDDEN;
    const int head = (n0 + wn * 64) >> 6;
    float av[4], rv[4];
#pragma unroll
    for (int j = 0; j < 4; ++j) {
      int gc = n0 + wn * 64 + j * 16 + lm;
      av[j] = alt[gc];
      rv[j] = art[gc];
    }
#pragma unroll
    for (int i = 0; i < 4; ++i)
#pragma unroll
      for (int r = 0; r < 4; ++r) {
        float pel = 0.f, per = 0.f;
#pragma unroll
        for (int j = 0; j < 4; ++j) {
          pel = fmaf(acc[i][j][r], av[j], pel);
          per = fmaf(acc[i][j][r], rv[j], per);
        }
#pragma unroll
        for (int o = 1; o < 16; o <<= 1) {
          pel += __shfl_xor(pel, o);
          per += __shfl_xor(per, o);
        }
        int row = m0 + wm * 64 + i * 16 + lg * 4 + r;
        if (lm == 0 && row < M) {
          el[((long)t * N_NODES + row) * 4 + head] = pel;  // single writer
          er[((long)t * N_NODES + row) * 4 + head] = per;
        }
      }
  }

  float bv[4];
  if (MODE == 2) {
#pragma unroll
    for (int j = 0; j < 4; ++j) bv[j] = bias[t * HIDDEN + n0 + wn * 64 + j * 16 + lm];
  }
  const int colOff = colOffT * t;
#pragma unroll
  for (int i = 0; i < 4; ++i)
#pragma unroll
    for (int r = 0; r < 4; ++r) {
      int row = m0 + wm * 64 + i * 16 + lg * 4 + r;
      if (row < M) {
#pragma unroll
        for (int j = 0; j < 4; ++j) {
          int col = n0 + wn * 64 + j * 16 + lm;
          float v = acc[i][j][r];
          if (MODE == 2) v = fmaxf(v + bv[j], 0.f);
          if (OUTK == 1) {
            u16 hi, lo;
            bsplit(v, hi, lo);
            Ch[(long)t * strideC + (long)row * ldC + col] = hi;
            Cl[(long)t * strideC + (long)row * ldC + col] = lo;
          } else if (OUTK == 2) {
            Ch[(long)t * strideC + (long)row * ldC + col] = f2h(v);
          } else {
            Cf[(long)t * strideC + colOff + (long)row * ldC + col] = v;
          }
        }
      }
    }
}

// ============================ GAT aggregation (z fp16 in, bf16 hi/lo out) ============================
__launch_bounds__(256)
__global__ void gat_agg_kernel(const u16* __restrict__ z, const float* __restrict__ el,
                               const float* __restrict__ er, const int* __restrict__ row_ptr,
                               const int* __restrict__ srcs, const float* __restrict__ bias,
                               u16* __restrict__ Hh, u16* __restrict__ Hl) {
  int t = blockIdx.y;
  int wv = threadIdx.x >> 6, lane = threadIdx.x & 63;
  int dst = blockIdx.x * 4 + wv;
  if (dst >= N_NODES) return;
  const int* rp = row_ptr + t * (N_NODES + 1);
  int beg = rp[dst], end = rp[dst + 1];
  const float* elt = el + (long)t * N_NODES * 4;
  const u16* zt  = z + (long)t * N_NODES * HIDDEN;
  const int* st = srcs + (long)t * NEDGE;
  float4 erd = *(const float4*)(er + (long)t * N_NODES * 4 + (long)dst * 4);

  float m0 = -INFINITY, m1 = -INFINITY, m2 = -INFINITY, m3 = -INFINITY;
  for (int j = beg + lane; j < end; j += 64) {
    unsigned s = (unsigned)st[j];
    float4 ev = *(const float4*)(elt + (s << 2));
    m0 = fmaxf(m0, lrelu(ev.x + erd.x));
    m1 = fmaxf(m1, lrelu(ev.y + erd.y));
    m2 = fmaxf(m2, lrelu(ev.z + erd.z));
    m3 = fmaxf(m3, lrelu(ev.w + erd.w));
  }
#pragma unroll
  for (int off = 32; off; off >>= 1) {
    m0 = fmaxf(m0, __shfl_xor(m0, off));
    m1 = fmaxf(m1, __shfl_xor(m1, off));
    m2 = fmaxf(m2, __shfl_xor(m2, off));
    m3 = fmaxf(m3, __shfl_xor(m3, off));
  }
  float d0 = 0, d1 = 0, d2 = 0, d3 = 0;
  for (int j = beg + lane; j < end; j += 64) {
    unsigned s = (unsigned)st[j];
    float4 ev = *(const float4*)(elt + (s << 2));
    d0 += __expf(lrelu(ev.x + erd.x) - m0);
    d1 += __expf(lrelu(ev.y + erd.y) - m1);
    d2 += __expf(lrelu(ev.z + erd.z) - m2);
    d3 += __expf(lrelu(ev.w + erd.w) - m3);
  }
#pragma unroll
  for (int off = 32; off; off >>= 1) {
    d0 += __shfl_xor(d0, off);
    d1 += __shfl_xor(d1, off);
    d2 += __shfl_xor(d2, off);
    d3 += __shfl_xor(d3, off);
  }
  int hl = lane >> 4;
  float mh  = (hl == 0) ? m0 : (hl == 1) ? m1 : (hl == 2) ? m2 : m3;
  float dh  = (hl == 0) ? d0 : (hl == 1) ? d1 : (hl == 2) ? d2 : d3;
  float erh = (hl == 0) ? erd.x : (hl == 1) ? erd.y : (hl == 2) ? erd.z : erd.w;
  float inv = 1.0f / fmaxf(dh, 1e-9f);
  float a0 = 0, a1 = 0, a2 = 0, a3 = 0;
  for (int j = beg; j < end; ++j) {
    unsigned s = (unsigned)st[j];
    float eh = lrelu(elt[(s << 2) + hl] + erh);
    float w = __expf(eh - mh) * inv;
    uint2 zp = *(const uint2*)(zt + (s << 8) + (lane << 2));
    float2 f0 = __half22float2(*(__half2*)&zp.x);
    float2 f1 = __half22float2(*(__half2*)&zp.y);
    a0 = fmaf(w, f0.x, a0);
    a1 = fmaf(w, f0.y, a1);
    a2 = fmaf(w, f1.x, a2);
    a3 = fmaf(w, f1.y, a3);
  }
  float4 bv = *(const float4*)(bias + t * HIDDEN + lane * 4);
  float o0 = fmaxf(a0 + bv.x, 0.f);
  float o1 = fmaxf(a1 + bv.y, 0.f);
  float o2 = fmaxf(a2 + bv.z, 0.f);
  float o3 = fmaxf(a3 + bv.w, 0.f);
  ushort4 hi, lo;
  bsplit(o0, hi.x, lo.x);
  bsplit(o1, hi.y, lo.y);
  bsplit(o2, hi.z, lo.z);
  bsplit(o3, hi.w, lo.w);
  long ob = (long)t * N_NODES * HIDDEN + (long)dst * HIDDEN + lane * 4;
  *(ushort4*)(Hh + ob) = hi;
  *(ushort4*)(Hl + ob) = lo;
}

// ============================ GIN aggregation on P (fp16 in, fp32 out) ============================
// y = (1+eps)*P[dst] + sum_{src} P[src] + b1
__launch_bounds__(256)
__global__ void gin_agg_kernel(const u16* __restrict__ P, const int* __restrict__ row_ptr,
                               const int* __restrict__ srcs, const float* __restrict__ epsArr,
                               const float* __restrict__ b1, float* __restrict__ y) {
  int t = blockIdx.y;
  int wv = threadIdx.x >> 6, lane = threadIdx.x & 63;
  int dst = blockIdx.x * 4 + wv;
  if (dst >= N_NODES) return;
  const int* rp = row_ptr + t * (N_NODES + 1);
  int beg = rp[dst], end = rp[dst + 1];
  const u16* Pt = P + (long)t * N_NODES * HIDDEN;
  const int* st = srcs + (long)t * NEDGE;
  float ep = 1.0f + epsArr[t];
  float a0 = 0, a1 = 0, a2 = 0, a3 = 0;
  for (int j = beg; j < end; ++j) {
    unsigned s = (unsigned)st[j];
    uint2 pp = *(const uint2*)(Pt + (s << 8) + (lane << 2));
    float2 f0 = __half22float2(*(__half2*)&pp.x);
    float2 f1 = __half22float2(*(__half2*)&pp.y);
    a0 += f0.x; a1 += f0.y; a2 += f1.x; a3 += f1.y;
  }
  uint2 sp = *(const uint2*)(Pt + ((unsigned)dst << 8) + (lane << 2));
  float2 s0 = __half22float2(*(__half2*)&sp.x);
  float2 s1 = __half22float2(*(__half2*)&sp.y);
  float4 bb = *(const float4*)(b1 + t * HIDDEN + lane * 4);
  float4 o;
  o.x = fmaf(ep, s0.x, a0) + bb.x;
  o.y = fmaf(ep, s0.y, a1) + bb.y;
  o.z = fmaf(ep, s1.x, a2) + bb.z;
  o.w = fmaf(ep, s1.y, a3) + bb.w;
  *(float4*)(y + (long)t * N_NODES * HIDDEN + (long)dst * HIDDEN + lane * 4) = o;
}

// ============================ BN stats (two-level, no atomics) ============================
__launch_bounds__(256)
__global__ void stats_kernel(const float* __restrict__ y, long strideY,
                             float* __restrict__ partials) {  // [T][SNB][512]
  const int t = blockIdx.y, blk = blockIdx.x;
  const int tid = threadIdx.x;
  const int col4 = (tid & 63) * 4;
  const int rsub = tid >> 6;
  const int chunk = (N_NODES + SNB - 1) / SNB;
  const int r0 = blk * chunk;
  const int rend = min(r0 + chunk, N_NODES);
  const float* yt = y + (long)t * strideY;
  float s[4] = {0.f, 0.f, 0.f, 0.f}, s2[4] = {0.f, 0.f, 0.f, 0.f};
  for (int r = r0 + rsub; r < rend; r += 4) {
    float4 v = *(const float4*)(yt + (long)r * HIDDEN + col4);
    s[0] += v.x; s2[0] = fmaf(v.x, v.x, s2[0]);
    s[1] += v.y; s2[1] = fmaf(v.y, v.y, s2[1]);
    s[2] += v.z; s2[2] = fmaf(v.z, v.z, s2[2]);
    s[3] += v.w; s2[3] = fmaf(v.w, v.w, s2[3]);
  }
  __shared__ float ls[4][512];
#pragma unroll
  for (int e = 0; e < 4; ++e) {
    ls[rsub][col4 + e] = s[e];
    ls[rsub][256 + col4 + e] = s2[e];
  }
  __syncthreads();
  for (int i = tid; i < 512; i += 256) {
    float v = ls[0][i] + ls[1][i] + ls[2][i] + ls[3][i];
    partials[((long)t * SNB + blk) * 512 + i] = v;
  }
}

__global__ void bn_finalize_kernel(const float* __restrict__ partials,
                                   const float* __restrict__ g1, const float* __restrict__ be1,
                                   float* __restrict__ scale, float* __restrict__ shift) {
  int i = threadIdx.x + blockIdx.x * blockDim.x;
  if (i >= NTYPE * HIDDEN) return;
  int t = i / HIDDEN, c = i % HIDDEN;
  float s = 0.f, s2 = 0.f;
  for (int b = 0; b < SNB; ++b) {
    s  += partials[((long)t * SNB + b) * 512 + c];
    s2 += partials[((long)t * SNB + b) * 512 + 256 + c];
  }
  float mu  = s * (1.0f / N_NODES);
  float ms  = s2 * (1.0f / N_NODES);
  float var = ms - mu * mu;
  float sc = g1[i] * rsqrtf(var + 1e-5f);
  scale[i] = sc;
  shift[i] = be1[i] - mu * sc;
}

// ============================ launch ============================
extern "C" void kernel_launch(void* const* d_in, const int* in_sizes, int n_in,
                              void* d_out, int out_size, void* d_ws, size_t ws_size,
                              hipStream_t stream) {
  const float* feats   = (const float*)d_in[0];
  const int* src0      = (const int*)d_in[1];
  const int* dst0      = (const int*)d_in[2];
  const int* src1      = (const int*)d_in[3];
  const int* dst1      = (const int*)d_in[4];
  const float* gat0_W  = (const float*)d_in[5];
  const float* gat0_al = (const float*)d_in[6];
  const float* gat0_ar = (const float*)d_in[7];
  const float* gat0_b  = (const float*)d_in[8];
  const float* gat1_W  = (const float*)d_in[9];
  const float* gat1_al = (const float*)d_in[10];
  const float* gat1_ar = (const float*)d_in[11];
  const float* gat1_b  = (const float*)d_in[12];
  const float* gin0_eps = (const float*)d_in[13];
  const float* gin0_W1  = (const float*)d_in[14];
  const float* gin0_b1  = (const float*)d_in[15];
  const float* gin0_g1  = (const float*)d_in[16];
  const float* gin0_be1 = (const float*)d_in[17];
  const float* gin0_W2  = (const float*)d_in[18];
  const float* gin0_b2  = (const float*)d_in[19];
  const float* gin1_eps = (const float*)d_in[20];
  const float* gin1_W1  = (const float*)d_in[21];
  const float* gin1_b1  = (const float*)d_in[22];
  const float* gin1_g1  = (const float*)d_in[23];
  const float* gin1_be1 = (const float*)d_in[24];
  const float* gin1_W2  = (const float*)d_in[25];
  const float* gin1_b2  = (const float*)d_in[26];
  float* out = (float*)d_out;

  char* p = (char*)d_ws;
  size_t off = 0;
  auto take = [&](size_t bytes) -> void* {
    void* r = p + off;
    off = (off + bytes + 255) & ~(size_t)255;
    return r;
  };
  float* bufA  = (float*)take((size_t)NTYPE * N_NODES * HIDDEN * 4);  // y (fp32)
  u16*   bufZ  = (u16*)take((size_t)NTYPE * N_NODES * HIDDEN * 2);    // z / P (fp16)
  u16*   bufCh = (u16*)take((size_t)NTYPE * N_NODES * HIDDEN * 2);    // h hi (bf16)
  u16*   bufCl = (u16*)take((size_t)NTYPE * N_NODES * HIDDEN * 2);    // h lo
  u16*   fhi   = (u16*)take((size_t)N_NODES * F_IN * 2);
  u16*   flo   = (u16*)take((size_t)N_NODES * F_IN * 2);
  float* el   = (float*)take((size_t)NTYPE * N_NODES * 4 * 4);
  float* er   = (float*)take((size_t)NTYPE * N_NODES * 4 * 4);
  int* counts  = (int*)take((size_t)NTYPE * N_NODES * 4);
  int* row_ptr = (int*)take((size_t)NTYPE * (N_NODES + 1) * 4);
  int* cursor  = (int*)take((size_t)NTYPE * N_NODES * 4);
  int* srcs    = (int*)take((size_t)NTYPE * NEDGE * 4);
  float* bn_part  = (float*)take((size_t)NTYPE * SNB * 512 * 4);
  float* bn_scale = (float*)take((size_t)NTYPE * HIDDEN * 4);
  float* bn_shift = (float*)take((size_t)NTYPE * HIDDEN * 4);
  u16* bh_g0   = (u16*)take((size_t)NTYPE * 256 * 128 * 2);
  u16* bl_g0   = (u16*)take((size_t)NTYPE * 256 * 128 * 2);
  u16* bh_g1   = (u16*)take((size_t)NTYPE * 256 * 256 * 2);
  u16* bl_g1   = (u16*)take((size_t)NTYPE * 256 * 256 * 2);
  u16* bh_i0w1 = (u16*)take((size_t)NTYPE * 256 * 384 * 2);
  u16* bl_i0w1 = (u16*)take((size_t)NTYPE * 256 * 384 * 2);
  u16* bh_i0w2 = (u16*)take((size_t)NTYPE * 256 * 256 * 2);
  u16* bl_i0w2 = (u16*)take((size_t)NTYPE * 256 * 256 * 2);
  u16* bh_i1w1 = (u16*)take((size_t)NTYPE * 256 * 256 * 2);
  u16* bl_i1w1 = (u16*)take((size_t)NTYPE * 256 * 256 * 2);
  u16* bh_i1w2 = (u16*)take((size_t)NTYPE * 256 * 256 * 2);
  u16* bl_i1w2 = (u16*)take((size_t)NTYPE * 256 * 256 * 2);
  (void)ws_size; (void)in_sizes; (void)n_in; (void)out_size;

  const dim3 blk(256);
  const int egrid = (NEDGE + 255) / 256;
  const dim3 ggrid((N_NODES + 127) / 128, 2, NTYPE);
  const dim3 agrid((N_NODES + 3) / 4, NTYPE);
  const dim3 sgrid(SNB, NTYPE);
  const long sN256 = (long)N_NODES * HIDDEN;

  // ---- prep ----
  prep_feats_kernel<<<(N_NODES * F_IN / 4 + 255) / 256, blk, 0, stream>>>(feats, fhi, flo);
  prep_b_kernel<<<dim3(2, 4, NTYPE), blk, 0, stream>>>(gat0_W, bh_g0, bl_g0, 128);
  prep_b_kernel<<<dim3(4, 4, NTYPE), blk, 0, stream>>>(gat1_W, bh_g1, bl_g1, 256);
  prep_b_kernel<<<dim3(6, 4, NTYPE), blk, 0, stream>>>(gin0_W1, bh_i0w1, bl_i0w1, 384);
  prep_b_kernel<<<dim3(4, 4, NTYPE), blk, 0, stream>>>(gin0_W2, bh_i0w2, bl_i0w2, 256);
  prep_b_kernel<<<dim3(4, 4, NTYPE), blk, 0, stream>>>(gin1_W1, bh_i1w1, bl_i1w1, 256);
  prep_b_kernel<<<dim3(4, 4, NTYPE), blk, 0, stream>>>(gin1_W2, bh_i1w2, bl_i1w2, 256);

  // ---- CSR build ----
  hipMemsetAsync(counts, 0, (size_t)NTYPE * N_NODES * 4, stream);
  hist_kernel<<<dim3(egrid, NTYPE), blk, 0, stream>>>(dst0, dst1, counts);
  scan_kernel<<<NTYPE, 1024, 0, stream>>>(counts, row_ptr, cursor);
  scatter_kernel<<<dim3(egrid, NTYPE), blk, 0, stream>>>(src0, dst0, src1, dst1, cursor, srcs);

  // ---- GAT layer 0 ----
  gemm_mfma<0, true, 2><<<ggrid, blk, 0, stream>>>(nullptr,
      fhi, flo, 0L, F_IN, F_IN, nullptr, nullptr, 0L, 0, 0L, F_IN,
      bh_g0, bl_g0, nullptr, nullptr, bufZ, nullptr, sN256, HIDDEN, 0,
      gat0_al, gat0_ar, el, er, nullptr, nullptr, N_NODES);
  gat_agg_kernel<<<agrid, blk, 0, stream>>>(bufZ, el, er, row_ptr, srcs, gat0_b, bufCh, bufCl);

  // ---- GAT layer 1 ----
  gemm_mfma<0, true, 2><<<ggrid, blk, 0, stream>>>(nullptr,
      bufCh, bufCl, sN256, HIDDEN, HIDDEN, nullptr, nullptr, 0L, 0, 0L, HIDDEN,
      bh_g1, bl_g1, nullptr, nullptr, bufZ, nullptr, sN256, HIDDEN, 0,
      gat1_al, gat1_ar, el, er, nullptr, nullptr, N_NODES);
  gat_agg_kernel<<<agrid, blk, 0, stream>>>(bufZ, el, er, row_ptr, srcs, gat1_b, bufCh, bufCl);

  // ---- GIN layer 0: P = [h | feats] @ W1 (K=384), then aggregate P ----
  gemm_mfma<1, true, 2><<<ggrid, blk, 0, stream>>>(nullptr,
      bufCh, bufCl, sN256, HIDDEN, HIDDEN, fhi, flo, 0L, F_IN, 0L, HIDDEN + F_IN,
      bh_i0w1, bl_i0w1, nullptr, nullptr, bufZ, nullptr, sN256, HIDDEN, 0,
      nullptr, nullptr, nullptr, nullptr, nullptr, nullptr, N_NODES);
  gin_agg_kernel<<<agrid, blk, 0, stream>>>(bufZ, row_ptr, srcs, gin0_eps, gin0_b1, bufA);
  stats_kernel<<<sgrid, blk, 0, stream>>>(bufA, sN256, bn_part);
  bn_finalize_kernel<<<1, NTYPE * HIDDEN, 0, stream>>>(bn_part, gin0_g1, gin0_be1, bn_scale, bn_shift);
  gemm_mfma<2, false, 1><<<ggrid, blk, 0, stream>>>(bufA,
      nullptr, nullptr, 0L, HIDDEN, HIDDEN, nullptr, nullptr, 0L, 0, sN256, HIDDEN,
      bh_i0w2, bl_i0w2, gin0_b2, nullptr, bufCh, bufCl, sN256, HIDDEN, 0,
      nullptr, nullptr, nullptr, nullptr, bn_scale, bn_shift, N_NODES);

  // ---- GIN layer 1 ----
  gemm_mfma<1, true, 2><<<ggrid, blk, 0, stream>>>(nullptr,
      bufCh, bufCl, sN256, HIDDEN, HIDDEN, nullptr, nullptr, 0L, 0, 0L, HIDDEN,
      bh_i1w1, bl_i1w1, nullptr, nullptr, bufZ, nullptr, sN256, HIDDEN, 0,
      nullptr, nullptr, nullptr, nullptr, nullptr, nullptr, N_NODES);
  gin_agg_kernel<<<agrid, blk, 0, stream>>>(bufZ, row_ptr, srcs, gin1_eps, gin1_b1, bufA);
  stats_kernel<<<sgrid, blk, 0, stream>>>(bufA, sN256, bn_part);
  bn_finalize_kernel<<<1, NTYPE * HIDDEN, 0, stream>>>(bn_part, gin1_g1, gin1_be1, bn_scale, bn_shift);
  gemm_mfma<2, false, 0><<<ggrid, blk, 0, stream>>>(bufA,
      nullptr, nullptr, 0L, HIDDEN, HIDDEN, nullptr, nullptr, 0L, 0, sN256, HIDDEN,
      bh_i1w2, bl_i1w2, gin1_b2, out, nullptr, nullptr, 0L, NTYPE * HIDDEN, HIDDEN,
      nullptr, nullptr, nullptr, nullptr, bn_scale, bn_shift, N_NODES);
}